// Round 4
// baseline (6387.901 us; speedup 1.0000x reference)
//
#include <hip/hip_runtime.h>
#include <hip/hip_cooperative_groups.h>
#include <math.h>

namespace cg = cooperative_groups;
typedef unsigned long long u64;

#define NN 4096
#define LBL 343
#define U64MAX 0xFFFFFFFFFFFFFFFFull

// ---------------------------------------------------------------------------
// Kernel 1 (cooperative): Boruvka MST. Unique MST == Prim's tree (distinct
// weights a.s.). Per round: every row scanned by one wave (64 lanes x 16
// float4), per-component min outgoing edge via packed u64 atomicMin
// (wbits<<24 | u<<12 | v), hook + 2-cycle break, pointer-jump compress.
// ---------------------------------------------------------------------------
__global__ __launch_bounds__(1024) void mrf_boruvka_kernel(
    const float* __restrict__ dist,
    int* __restrict__ comp, u64* __restrict__ minE, int* __restrict__ hook,
    int* __restrict__ eu, int* __restrict__ ev, unsigned* __restrict__ ew,
    int* __restrict__ counters /* [0]=edge count, [1]=component count */)
{
  cg::grid_group grid = cg::this_grid();
  const int gtid = blockIdx.x * 1024 + threadIdx.x;
  const int gsize = gridDim.x * 1024;

  for (int i = gtid; i < NN; i += gsize) { comp[i] = i; minE[i] = U64MAX; }
  if (gtid == 0) { counters[0] = 0; counters[1] = NN; }
  __threadfence();
  grid.sync();

  for (int round = 0; round < 13; ++round) {
    if (((volatile int*)counters)[1] <= 1) break;

    // ---- phase 1: per-row min outgoing edge, reduce into component slot ----
    {
      const int i = gtid >> 6;        // one wave per row (4096 waves exactly)
      const int lane = gtid & 63;
      const int ci = comp[i];
      const float4* rowp = (const float4*)(dist + (size_t)i * NN);
      const int4* cp = (const int4*)comp;
      u64 best = U64MAX;
      #pragma unroll 4
      for (int k = 0; k < 16; ++k) {
        const int q = k * 64 + lane;
        const float4 dv = rowp[q];
        const int4 cv = cp[q];
        const int j0 = q * 4;
        if (cv.x != ci) { const u64 p = ((u64)__float_as_uint(dv.x) << 24) | ((u64)i << 12) | (u64)(j0    ); best = best < p ? best : p; }
        if (cv.y != ci) { const u64 p = ((u64)__float_as_uint(dv.y) << 24) | ((u64)i << 12) | (u64)(j0 + 1); best = best < p ? best : p; }
        if (cv.z != ci) { const u64 p = ((u64)__float_as_uint(dv.z) << 24) | ((u64)i << 12) | (u64)(j0 + 2); best = best < p ? best : p; }
        if (cv.w != ci) { const u64 p = ((u64)__float_as_uint(dv.w) << 24) | ((u64)i << 12) | (u64)(j0 + 3); best = best < p ? best : p; }
      }
      #pragma unroll
      for (int sh = 32; sh >= 1; sh >>= 1) {
        const u64 o = __shfl_down(best, sh);
        best = best < o ? best : o;
      }
      if (lane == 0 && best != U64MAX) atomicMin(&minE[ci], best);
    }
    __threadfence();
    grid.sync();

    // ---- phase 2: hooking with mutual-pair (2-cycle) break, record edges ----
    for (int i = gtid; i < NN; i += gsize) {
      int h = comp[i];
      if (h == i) {
        const u64 e = minE[i];
        if (e != U64MAX) {
          const int v = (int)(e & 0xFFF);
          const int u = (int)((e >> 12) & 0xFFF);
          const unsigned wb = (unsigned)(e >> 24);
          const int t = comp[v];
          const u64 te = minE[t];
          const int tv = (int)(te & 0xFFF);
          const bool mutual = (te != U64MAX) && (comp[tv] == i);
          if (!(mutual && i < t)) {           // mutual pair: smaller root stays
            h = t;
            const int slot = atomicAdd(&counters[0], 1);
            eu[slot] = u; ev[slot] = v; ew[slot] = wb;
          }
        }
      }
      hook[i] = h;
    }
    if (gtid == 0) counters[1] = 0;
    __threadfence();
    grid.sync();

    // ---- phase 3: compress by chasing hook[] (acyclic), count roots ----
    for (int i = gtid; i < NN; i += gsize) {
      int c = hook[i];
      int guard = 0;
      while (hook[c] != c && guard++ < NN) c = hook[c];
      comp[i] = c;
      minE[i] = U64MAX;
      if (c == i) atomicAdd(&counters[1], 1);
    }
    __threadfence();
    grid.sync();
  }
}

// ---------------------------------------------------------------------------
// block-wide exclusive scan over 4096 LDS ints (1024 threads, 4/thread)
// ---------------------------------------------------------------------------
__device__ __forceinline__ void scan4096(int* arr, int* tmp16, int tid)
{
  __syncthreads();
  const int base = tid * 4;
  const int c0 = arr[base], c1 = arr[base + 1], c2 = arr[base + 2], c3 = arr[base + 3];
  const int lsum = c0 + c1 + c2 + c3;
  const int lane = tid & 63, wid = tid >> 6;
  int incl = lsum;
  #pragma unroll
  for (int o = 1; o < 64; o <<= 1) {
    const int t = __shfl_up(incl, o);
    if (lane >= o) incl += t;
  }
  if (lane == 63) tmp16[wid] = incl;
  __syncthreads();
  if (tid == 0) {
    int run = 0;
    for (int w = 0; w < 16; ++w) { const int t = tmp16[w]; tmp16[w] = run; run += t; }
  }
  __syncthreads();
  const int excl = tmp16[wid] + incl - lsum;
  arr[base]     = excl;
  arr[base + 1] = excl + c0;
  arr[base + 2] = excl + c0 + c1;
  arr[base + 3] = excl + c0 + c1 + c2;
  __syncthreads();
}

// ---------------------------------------------------------------------------
// Kernel 2 (single block, 1024 thr): root MST at node 0.
// - CSR adjacency from edge list (entries packed (wbits<<12)|nbr as u64)
// - BFS for parent[]/depth[] (tree => race-free discovery)
// - child lists sorted DESCENDING by (wbits, idx)  == reversed Prim order
// - per-depth node buckets (levStart/levNodes) for the solve schedule
// - w_edge[c] = expf(-dist[c][parent]/0.18f)
// - zeroes ready[] for the dataflow solve (ws is not re-poisoned per replay)
// ---------------------------------------------------------------------------
__global__ __launch_bounds__(1024) void mrf_root_kernel(
    const float* __restrict__ dist,
    const int* __restrict__ eu, const int* __restrict__ ev, const unsigned* __restrict__ ew,
    int* __restrict__ parent_g, int* __restrict__ childStart, int* __restrict__ childList,
    int* __restrict__ levStart, int* __restrict__ levNodes,
    int* __restrict__ meta, float* __restrict__ w_edge,
    u64* __restrict__ adjList, int* __restrict__ ready)
{
  __shared__ int s_deg[NN];                 // 16 KB
  __shared__ int s_start[NN];               // 16 KB (adj CSR start; later level cursor)
  __shared__ int s_cur[NN];                 // 16 KB (adj cursor; later level counts)
  __shared__ int s_parent[NN];              // 16 KB
  __shared__ unsigned short s_dep[NN];      // 8 KB
  __shared__ unsigned short s_fr[2][NN];    // 16 KB frontiers (reused as int* later)
  __shared__ int s_tmp16[16];
  __shared__ int s_fcnt, s_nf;

  const int tid = threadIdx.x;

  for (int j = tid; j < NN; j += 1024) ready[j] = 0;   // fresh every call

  // ---- adjacency ----
  for (int j = tid; j < NN; j += 1024) s_deg[j] = 0;
  __syncthreads();
  for (int e = tid; e < NN - 1; e += 1024) {
    atomicAdd(&s_deg[eu[e] & (NN - 1)], 1);
    atomicAdd(&s_deg[ev[e] & (NN - 1)], 1);
  }
  __syncthreads();
  for (int j = tid; j < NN; j += 1024) s_start[j] = s_deg[j];
  scan4096(s_start, s_tmp16, tid);
  for (int j = tid; j < NN; j += 1024) s_cur[j] = s_start[j];
  __syncthreads();
  for (int e = tid; e < NN - 1; e += 1024) {
    const int u = eu[e] & (NN - 1), v = ev[e] & (NN - 1);
    const u64 wb = (u64)ew[e];
    const int p1 = atomicAdd(&s_cur[u], 1);
    adjList[p1] = (wb << 12) | (u64)v;
    const int p2 = atomicAdd(&s_cur[v], 1);
    adjList[p2] = (wb << 12) | (u64)u;
  }
  __syncthreads();

  // ---- BFS from node 0 ----
  for (int j = tid; j < NN; j += 1024) { s_parent[j] = 0; s_dep[j] = 0; }
  if (tid == 0) { s_fcnt = 1; s_nf = 0; s_fr[0][0] = 0; }
  __syncthreads();
  int cur = 0, lev = 0;
  while (true) {
    const int fcnt = s_fcnt;
    if (fcnt == 0) break;
    for (int idx = tid; idx < fcnt; idx += 1024) {
      const int x = s_fr[cur][idx];
      const int st = s_start[x], dg = s_deg[x];
      for (int a = 0; a < dg; ++a) {
        const u64 ent = adjList[st + a];
        const int nb = (int)(ent & 0xFFF);
        if (nb != s_parent[x] || x == 0) {     // tree: each nb discovered once
          s_parent[nb] = x;
          s_dep[nb] = (unsigned short)(lev + 1);
          const int slot = atomicAdd(&s_nf, 1);
          s_fr[1 - cur][slot] = (unsigned short)nb;
        }
      }
    }
    __syncthreads();
    if (tid == 0) { s_fcnt = s_nf; s_nf = 0; }
    ++lev;
    cur ^= 1;
    __syncthreads();
  }
  const int numLev = lev;
  if (tid == 0) { s_parent[0] = 0; meta[0] = numLev; }
  __syncthreads();

  // ---- childStart (counts = deg - 1 for non-root) ----
  int* s_cs2 = (int*)s_fr;   // frontier memory reused (16 KB = 4096 ints)
  for (int j = tid; j < NN; j += 1024) s_cs2[j] = s_deg[j] - (j != 0 ? 1 : 0);
  scan4096(s_cs2, s_tmp16, tid);
  for (int j = tid; j < NN; j += 1024) childStart[j] = s_cs2[j];
  if (tid == 0) childStart[NN] = NN - 1;
  __syncthreads();

  // ---- children sorted descending by (wbits, idx) ----
  for (int p = tid; p < NN; p += 1024) {
    const int st = s_start[p], dg = s_deg[p], cs = s_cs2[p];
    const int par = s_parent[p];
    u64 buf[16];
    int m = 0;
    for (int a = 0; a < dg; ++a) {
      const u64 ent = adjList[st + a];
      const int nb = (int)(ent & 0xFFF);
      if (p != 0 && nb == par) continue;
      if (m < 16) {
        int q = m;
        while (q > 0 && buf[q - 1] < ent) { buf[q] = buf[q - 1]; --q; }
        buf[q] = ent;
        ++m;
      } else {
        childList[cs + m] = nb;  // unsorted overflow (deg>16: ~impossible)
        ++m;
      }
    }
    const int lim = m < 16 ? m : 16;
    for (int k = 0; k < lim; ++k) childList[cs + k] = (int)(buf[k] & 0xFFF);
  }

  // ---- level buckets ----
  for (int j = tid; j < NN; j += 1024) s_cur[j] = 0;
  __syncthreads();
  for (int j = tid; j < NN; j += 1024) atomicAdd(&s_cur[s_dep[j]], 1);
  scan4096(s_cur, s_tmp16, tid);
  for (int j = tid; j < NN; j += 1024) { levStart[j] = s_cur[j]; s_start[j] = s_cur[j]; }
  if (tid == 0) levStart[NN] = NN;
  __syncthreads();
  for (int j = tid; j < NN; j += 1024) {
    const int pos = atomicAdd(&s_start[s_dep[j]], 1);
    levNodes[pos] = j;
  }

  // ---- outputs ----
  for (int j = tid; j < NN; j += 1024) {
    parent_g[j] = s_parent[j];
    w_edge[j] = (j == 0) ? 0.0f
                         : expf(-dist[(size_t)j * NN + s_parent[j]] / 0.18f);
  }
}

// ---------------------------------------------------------------------------
// Kernel 3 (cooperative, dataflow): persistent blocks walk a static
// topological order (deepest level first). A node runs when ready[c] == deg
// (agent-scope acquire poll; producers threadfence + release-add). The block
// that completes the root then performs the downward backtracking.
// msgbuf aliases d_out (fully overwritten afterwards).
// ---------------------------------------------------------------------------
__global__ __launch_bounds__(384) void mrf_solve_kernel(
    const float* __restrict__ unary, const float* __restrict__ A,
    float* __restrict__ msgbuf, unsigned short* __restrict__ ptrbuf,
    const int* __restrict__ parent, const int* __restrict__ childStart,
    const int* __restrict__ childList, const int* __restrict__ levStart,
    const int* __restrict__ levNodes, const float* __restrict__ w_edge,
    int* __restrict__ labels, const int* __restrict__ meta,
    int* __restrict__ ready)
{
  __shared__ float s_b[LBL];
  __shared__ int s_lab[NN];
  __shared__ int s_children[64];
  const int tid = threadIdx.x;
  int numLev = meta[0];
  if (numLev < 1) numLev = 1;
  if (numLev > NN) numLev = NN;

  bool didRoot = false;

  // -------- upward (dataflow over topological positions) --------
  for (int p = blockIdx.x; p < NN; p += gridDim.x) {
    const int c = levNodes[NN - 1 - p] & (NN - 1);
    int cs = childStart[c], ce = childStart[c + 1];
    if (cs < 0) cs = 0;
    if (ce > NN - 1) ce = NN - 1;
    if (ce < cs) ce = cs;
    int deg = ce - cs;
    if (deg > 64) deg = 64;

    // wait for children
    if (tid == 0) {
      long long guard = 0;
      while (__hip_atomic_load(&ready[c], __ATOMIC_ACQUIRE,
                               __HIP_MEMORY_SCOPE_AGENT) < deg) {
        __builtin_amdgcn_s_sleep(2);
        if (++guard > 50000000LL) break;    // anti-hang escape (never expected)
      }
    }
    __syncthreads();
    if (tid < deg) s_children[tid] = childList[cs + tid] & (NN - 1);
    __syncthreads();

    // belief[c] = unary[c] + children messages, in reversed-Prim order
    if (tid < LBL) {
      float b = unary[(size_t)c * LBL + tid];
      for (int k = 0; k < deg; ++k)
        b = __fadd_rn(b, msgbuf[(size_t)s_children[k] * LBL + tid]);
      s_b[tid] = b;
    }
    __syncthreads();

    if (c != 0) {
      if (tid < LBL) {
        const float w = w_edge[c];
        const float* __restrict__ Ac = A + tid;
        // argmax over lc of s_b[lc] + w*A[lc][tid]; ascending lc, strict >
        float bv = __fadd_rn(s_b[0], __fmul_rn(w, Ac[0]));
        int bi = 0;
        int lc = 1;
        for (; lc < 7; ++lc) {               // peel to 8-aligned remainder
          const float s = __fadd_rn(s_b[lc], __fmul_rn(w, Ac[(size_t)lc * LBL]));
          if (s > bv) { bv = s; bi = lc; }
        }
        for (; lc + 8 <= LBL; lc += 8) {     // 42 groups of 8 independent loads
          const float a0 = Ac[(size_t)(lc + 0) * LBL];
          const float a1 = Ac[(size_t)(lc + 1) * LBL];
          const float a2 = Ac[(size_t)(lc + 2) * LBL];
          const float a3 = Ac[(size_t)(lc + 3) * LBL];
          const float a4 = Ac[(size_t)(lc + 4) * LBL];
          const float a5 = Ac[(size_t)(lc + 5) * LBL];
          const float a6 = Ac[(size_t)(lc + 6) * LBL];
          const float a7 = Ac[(size_t)(lc + 7) * LBL];
          const float s0 = __fadd_rn(s_b[lc + 0], __fmul_rn(w, a0));
          const float s1 = __fadd_rn(s_b[lc + 1], __fmul_rn(w, a1));
          const float s2 = __fadd_rn(s_b[lc + 2], __fmul_rn(w, a2));
          const float s3 = __fadd_rn(s_b[lc + 3], __fmul_rn(w, a3));
          const float s4 = __fadd_rn(s_b[lc + 4], __fmul_rn(w, a4));
          const float s5 = __fadd_rn(s_b[lc + 5], __fmul_rn(w, a5));
          const float s6 = __fadd_rn(s_b[lc + 6], __fmul_rn(w, a6));
          const float s7 = __fadd_rn(s_b[lc + 7], __fmul_rn(w, a7));
          if (s0 > bv) { bv = s0; bi = lc + 0; }
          if (s1 > bv) { bv = s1; bi = lc + 1; }
          if (s2 > bv) { bv = s2; bi = lc + 2; }
          if (s3 > bv) { bv = s3; bi = lc + 3; }
          if (s4 > bv) { bv = s4; bi = lc + 4; }
          if (s5 > bv) { bv = s5; bi = lc + 5; }
          if (s6 > bv) { bv = s6; bi = lc + 6; }
          if (s7 > bv) { bv = s7; bi = lc + 7; }
        }
        msgbuf[(size_t)c * LBL + tid] = bv;
        ptrbuf[(size_t)c * LBL + tid] = (unsigned short)bi;
      }
      __threadfence();
      __syncthreads();
      if (tid == 0)
        __hip_atomic_fetch_add(&ready[parent[c] & (NN - 1)], 1,
                               __ATOMIC_RELEASE, __HIP_MEMORY_SCOPE_AGENT);
    } else {
      if (tid == 0) {
        float bv = s_b[0]; int bi = 0;
        for (int l = 1; l < LBL; ++l)
          if (s_b[l] > bv) { bv = s_b[l]; bi = l; }
        labels[0] = bi;
      }
      __syncthreads();
      didRoot = true;   // all other nodes transitively complete
    }
  }

  // -------- downward backtracking (the block that finished the root) --------
  if (!didRoot) return;
  if (tid == 0) s_lab[0] = labels[0];
  __syncthreads();
  for (int lev = 1; lev < numLev; ++lev) {
    int ls = levStart[lev], le = levStart[lev + 1];
    if (ls < 0) ls = 0;
    if (le > NN) le = NN;
    for (int idx = ls + tid; idx < le; idx += 384) {
      const int c = levNodes[idx] & (NN - 1);
      int pl = s_lab[parent[c] & (NN - 1)];
      if (pl < 0) pl = 0;
      if (pl >= LBL) pl = LBL - 1;
      const int lab = (int)ptrbuf[(size_t)c * LBL + pl];
      s_lab[c] = lab;
      labels[c] = lab;
    }
    __syncthreads();
  }
}

// ---------------------------------------------------------------------------
// Kernel 4: output fill (2*onehot - 1) * 1e5 (overwrites all of d_out)
// ---------------------------------------------------------------------------
__global__ void mrf_out_kernel(const int* __restrict__ labels, float* __restrict__ out)
{
  const int id = blockIdx.x * blockDim.x + threadIdx.x;
  if (id >= NN * LBL) return;
  const int c = id / LBL;
  const int l = id - c * LBL;
  out[id] = (l == labels[c]) ? 100000.0f : -100000.0f;
}

extern "C" void kernel_launch(void* const* d_in, const int* in_sizes, int n_in,
                              void* d_out, int out_size, void* d_ws, size_t ws_size,
                              hipStream_t stream)
{
  (void)in_sizes; (void)n_in; (void)out_size; (void)ws_size;
  const float* unary = (const float*)d_in[0];
  const float* dist  = (const float*)d_in[1];
  const float* A     = (const float*)d_in[2];
  float* out = (float*)d_out;

  char* ws = (char*)d_ws;
  size_t off = 0;
  auto take = [&](size_t bytes) -> void* {
    void* p = (void*)(ws + off);
    off += (bytes + 255) & ~(size_t)255;
    return p;
  };
  float* msgbuf = out;   // aliases d_out; fully overwritten by mrf_out_kernel
  unsigned short* ptrbuf = (unsigned short*)take((size_t)NN * LBL * sizeof(unsigned short));
  int*      comp       = (int*)     take(NN * sizeof(int));
  u64*      minE       = (u64*)     take(NN * sizeof(u64));
  int*      hook       = (int*)     take(NN * sizeof(int));
  int*      eu         = (int*)     take(NN * sizeof(int));
  int*      ev         = (int*)     take(NN * sizeof(int));
  unsigned* ew         = (unsigned*)take(NN * sizeof(unsigned));
  int*      counters   = (int*)     take(256);
  int*      parent     = (int*)     take(NN * sizeof(int));
  int*      childStart = (int*)     take((NN + 1) * sizeof(int));
  int*      childList  = (int*)     take(NN * sizeof(int));
  int*      levStart   = (int*)     take((NN + 1) * sizeof(int));
  int*      levNodes   = (int*)     take(NN * sizeof(int));
  int*      labels     = (int*)     take(NN * sizeof(int));
  int*      meta       = (int*)     take(256);
  float*    w_edge     = (float*)   take(NN * sizeof(float));
  int*      ready      = (int*)     take(NN * sizeof(int));
  u64*      adjList    = (u64*)     take((size_t)2 * NN * sizeof(u64));

  {
    void* args[] = {
      (void*)&dist, (void*)&comp, (void*)&minE, (void*)&hook,
      (void*)&eu, (void*)&ev, (void*)&ew, (void*)&counters
    };
    hipLaunchCooperativeKernel((void*)mrf_boruvka_kernel, dim3(256), dim3(1024),
                               args, 0, stream);
  }

  hipLaunchKernelGGL(mrf_root_kernel, dim3(1), dim3(1024), 0, stream,
                     dist, eu, ev, ew, parent, childStart, childList,
                     levStart, levNodes, meta, w_edge, adjList, ready);

  {
    void* args[] = {
      (void*)&unary, (void*)&A, (void*)&msgbuf, (void*)&ptrbuf,
      (void*)&parent, (void*)&childStart, (void*)&childList,
      (void*)&levStart, (void*)&levNodes, (void*)&w_edge,
      (void*)&labels, (void*)&meta, (void*)&ready
    };
    hipLaunchCooperativeKernel((void*)mrf_solve_kernel, dim3(256), dim3(384),
                               args, 0, stream);
  }

  const int total = NN * LBL;
  hipLaunchKernelGGL(mrf_out_kernel, dim3((total + 255) / 256), dim3(256), 0, stream,
                     labels, out);
}

// Round 5
// 2576.737 us; speedup vs baseline: 2.4791x; 2.4791x over previous
//
#include <hip/hip_runtime.h>
#include <hip/hip_cooperative_groups.h>
#include <math.h>

namespace cg = cooperative_groups;
typedef unsigned long long u64;

#define NN 4096
#define LBL 343
#define PSTRIDE 344   // ptrbuf row stride (u16), even => aligned u32 pair stores
#define U64MAX 0xFFFFFFFFFFFFFFFFull

// ---------------------------------------------------------------------------
// Kernel 1 (cooperative): Boruvka MST (unchanged from round 3/4 — passing).
// ---------------------------------------------------------------------------
__global__ __launch_bounds__(1024) void mrf_boruvka_kernel(
    const float* __restrict__ dist,
    int* __restrict__ comp, u64* __restrict__ minE, int* __restrict__ hook,
    int* __restrict__ eu, int* __restrict__ ev, unsigned* __restrict__ ew,
    int* __restrict__ counters /* [0]=edge count, [1]=component count */)
{
  cg::grid_group grid = cg::this_grid();
  const int gtid = blockIdx.x * 1024 + threadIdx.x;
  const int gsize = gridDim.x * 1024;

  for (int i = gtid; i < NN; i += gsize) { comp[i] = i; minE[i] = U64MAX; }
  if (gtid == 0) { counters[0] = 0; counters[1] = NN; }
  __threadfence();
  grid.sync();

  for (int round = 0; round < 13; ++round) {
    if (((volatile int*)counters)[1] <= 1) break;

    // ---- phase 1: per-row min outgoing edge, reduce into component slot ----
    {
      const int i = gtid >> 6;        // one wave per row (4096 waves exactly)
      const int lane = gtid & 63;
      const int ci = comp[i];
      const float4* rowp = (const float4*)(dist + (size_t)i * NN);
      const int4* cp = (const int4*)comp;
      u64 best = U64MAX;
      #pragma unroll 4
      for (int k = 0; k < 16; ++k) {
        const int q = k * 64 + lane;
        const float4 dv = rowp[q];
        const int4 cv = cp[q];
        const int j0 = q * 4;
        if (cv.x != ci) { const u64 p = ((u64)__float_as_uint(dv.x) << 24) | ((u64)i << 12) | (u64)(j0    ); best = best < p ? best : p; }
        if (cv.y != ci) { const u64 p = ((u64)__float_as_uint(dv.y) << 24) | ((u64)i << 12) | (u64)(j0 + 1); best = best < p ? best : p; }
        if (cv.z != ci) { const u64 p = ((u64)__float_as_uint(dv.z) << 24) | ((u64)i << 12) | (u64)(j0 + 2); best = best < p ? best : p; }
        if (cv.w != ci) { const u64 p = ((u64)__float_as_uint(dv.w) << 24) | ((u64)i << 12) | (u64)(j0 + 3); best = best < p ? best : p; }
      }
      #pragma unroll
      for (int sh = 32; sh >= 1; sh >>= 1) {
        const u64 o = __shfl_down(best, sh);
        best = best < o ? best : o;
      }
      if (lane == 0 && best != U64MAX) atomicMin(&minE[ci], best);
    }
    __threadfence();
    grid.sync();

    // ---- phase 2: hooking with mutual-pair (2-cycle) break, record edges ----
    for (int i = gtid; i < NN; i += gsize) {
      int h = comp[i];
      if (h == i) {
        const u64 e = minE[i];
        if (e != U64MAX) {
          const int v = (int)(e & 0xFFF);
          const int u = (int)((e >> 12) & 0xFFF);
          const unsigned wb = (unsigned)(e >> 24);
          const int t = comp[v];
          const u64 te = minE[t];
          const int tv = (int)(te & 0xFFF);
          const bool mutual = (te != U64MAX) && (comp[tv] == i);
          if (!(mutual && i < t)) {           // mutual pair: smaller root stays
            h = t;
            const int slot = atomicAdd(&counters[0], 1);
            eu[slot] = u; ev[slot] = v; ew[slot] = wb;
          }
        }
      }
      hook[i] = h;
    }
    if (gtid == 0) counters[1] = 0;
    __threadfence();
    grid.sync();

    // ---- phase 3: compress by chasing hook[] (acyclic), count roots ----
    for (int i = gtid; i < NN; i += gsize) {
      int c = hook[i];
      int guard = 0;
      while (hook[c] != c && guard++ < NN) c = hook[c];
      comp[i] = c;
      minE[i] = U64MAX;
      if (c == i) atomicAdd(&counters[1], 1);
    }
    __threadfence();
    grid.sync();
  }
}

// ---------------------------------------------------------------------------
// block-wide exclusive scan over 4096 LDS ints (1024 threads, 4/thread)
// ---------------------------------------------------------------------------
__device__ __forceinline__ void scan4096(int* arr, int* tmp16, int tid)
{
  __syncthreads();
  const int base = tid * 4;
  const int c0 = arr[base], c1 = arr[base + 1], c2 = arr[base + 2], c3 = arr[base + 3];
  const int lsum = c0 + c1 + c2 + c3;
  const int lane = tid & 63, wid = tid >> 6;
  int incl = lsum;
  #pragma unroll
  for (int o = 1; o < 64; o <<= 1) {
    const int t = __shfl_up(incl, o);
    if (lane >= o) incl += t;
  }
  if (lane == 63) tmp16[wid] = incl;
  __syncthreads();
  if (tid == 0) {
    int run = 0;
    for (int w = 0; w < 16; ++w) { const int t = tmp16[w]; tmp16[w] = run; run += t; }
  }
  __syncthreads();
  const int excl = tmp16[wid] + incl - lsum;
  arr[base]     = excl;
  arr[base + 1] = excl + c0;
  arr[base + 2] = excl + c0 + c1;
  arr[base + 3] = excl + c0 + c1 + c2;
  __syncthreads();
}

// ---------------------------------------------------------------------------
// Kernel 2 (single block): root MST at 0, child lists desc-(wbits,idx)
// (== reversed Prim order), level buckets, w_edge, zero ready[].
// ---------------------------------------------------------------------------
__global__ __launch_bounds__(1024) void mrf_root_kernel(
    const float* __restrict__ dist,
    const int* __restrict__ eu, const int* __restrict__ ev, const unsigned* __restrict__ ew,
    int* __restrict__ parent_g, int* __restrict__ childStart, int* __restrict__ childList,
    int* __restrict__ levStart, int* __restrict__ levNodes,
    int* __restrict__ meta, float* __restrict__ w_edge,
    u64* __restrict__ adjList, int* __restrict__ ready)
{
  __shared__ int s_deg[NN];
  __shared__ int s_start[NN];
  __shared__ int s_cur[NN];
  __shared__ int s_parent[NN];
  __shared__ unsigned short s_dep[NN];
  __shared__ unsigned short s_fr[2][NN];
  __shared__ int s_tmp16[16];
  __shared__ int s_fcnt, s_nf;

  const int tid = threadIdx.x;

  for (int j = tid; j < NN; j += 1024) ready[j] = 0;   // fresh every call

  // ---- adjacency ----
  for (int j = tid; j < NN; j += 1024) s_deg[j] = 0;
  __syncthreads();
  for (int e = tid; e < NN - 1; e += 1024) {
    atomicAdd(&s_deg[eu[e] & (NN - 1)], 1);
    atomicAdd(&s_deg[ev[e] & (NN - 1)], 1);
  }
  __syncthreads();
  for (int j = tid; j < NN; j += 1024) s_start[j] = s_deg[j];
  scan4096(s_start, s_tmp16, tid);
  for (int j = tid; j < NN; j += 1024) s_cur[j] = s_start[j];
  __syncthreads();
  for (int e = tid; e < NN - 1; e += 1024) {
    const int u = eu[e] & (NN - 1), v = ev[e] & (NN - 1);
    const u64 wb = (u64)ew[e];
    const int p1 = atomicAdd(&s_cur[u], 1);
    adjList[p1] = (wb << 12) | (u64)v;
    const int p2 = atomicAdd(&s_cur[v], 1);
    adjList[p2] = (wb << 12) | (u64)u;
  }
  __syncthreads();

  // ---- BFS from node 0 ----
  for (int j = tid; j < NN; j += 1024) { s_parent[j] = 0; s_dep[j] = 0; }
  if (tid == 0) { s_fcnt = 1; s_nf = 0; s_fr[0][0] = 0; }
  __syncthreads();
  int cur = 0, lev = 0;
  while (true) {
    const int fcnt = s_fcnt;
    if (fcnt == 0) break;
    for (int idx = tid; idx < fcnt; idx += 1024) {
      const int x = s_fr[cur][idx];
      const int st = s_start[x], dg = s_deg[x];
      for (int a = 0; a < dg; ++a) {
        const u64 ent = adjList[st + a];
        const int nb = (int)(ent & 0xFFF);
        if (nb != s_parent[x] || x == 0) {     // tree: each nb discovered once
          s_parent[nb] = x;
          s_dep[nb] = (unsigned short)(lev + 1);
          const int slot = atomicAdd(&s_nf, 1);
          s_fr[1 - cur][slot] = (unsigned short)nb;
        }
      }
    }
    __syncthreads();
    if (tid == 0) { s_fcnt = s_nf; s_nf = 0; }
    ++lev;
    cur ^= 1;
    __syncthreads();
  }
  const int numLev = lev;
  if (tid == 0) { s_parent[0] = 0; meta[0] = numLev; }
  __syncthreads();

  // ---- childStart ----
  int* s_cs2 = (int*)s_fr;
  for (int j = tid; j < NN; j += 1024) s_cs2[j] = s_deg[j] - (j != 0 ? 1 : 0);
  scan4096(s_cs2, s_tmp16, tid);
  for (int j = tid; j < NN; j += 1024) childStart[j] = s_cs2[j];
  if (tid == 0) childStart[NN] = NN - 1;
  __syncthreads();

  // ---- children sorted descending by (wbits, idx) ----
  for (int p = tid; p < NN; p += 1024) {
    const int st = s_start[p], dg = s_deg[p], cs = s_cs2[p];
    const int par = s_parent[p];
    u64 buf[16];
    int m = 0;
    for (int a = 0; a < dg; ++a) {
      const u64 ent = adjList[st + a];
      const int nb = (int)(ent & 0xFFF);
      if (p != 0 && nb == par) continue;
      if (m < 16) {
        int q = m;
        while (q > 0 && buf[q - 1] < ent) { buf[q] = buf[q - 1]; --q; }
        buf[q] = ent;
        ++m;
      } else {
        childList[cs + m] = nb;
        ++m;
      }
    }
    const int lim = m < 16 ? m : 16;
    for (int k = 0; k < lim; ++k) childList[cs + k] = (int)(buf[k] & 0xFFF);
  }

  // ---- level buckets ----
  for (int j = tid; j < NN; j += 1024) s_cur[j] = 0;
  __syncthreads();
  for (int j = tid; j < NN; j += 1024) atomicAdd(&s_cur[s_dep[j]], 1);
  scan4096(s_cur, s_tmp16, tid);
  for (int j = tid; j < NN; j += 1024) { levStart[j] = s_cur[j]; s_start[j] = s_cur[j]; }
  if (tid == 0) levStart[NN] = NN;
  __syncthreads();
  for (int j = tid; j < NN; j += 1024) {
    const int pos = atomicAdd(&s_start[s_dep[j]], 1);
    levNodes[pos] = j;
  }

  // ---- outputs ----
  for (int j = tid; j < NN; j += 1024) {
    parent_g[j] = s_parent[j];
    w_edge[j] = (j == 0) ? 0.0f
                         : expf(-dist[(size_t)j * NN + s_parent[j]] / 0.18f);
  }
}

// ---------------------------------------------------------------------------
// Kernel 3 (cooperative, dataflow via write-through L3 atomics):
// - poll ready[c] with RELAXED agent loads (read-through, NO invalidate)
// - msg/ptr cross-block data moved ONLY via relaxed agent atomics (sc1)
// - producer: relaxed sc1 stores, then one RELEASE agent fetch_add
// => no acquire fences, no L2 invalidation: A stays cache-resident.
// ---------------------------------------------------------------------------
__global__ __launch_bounds__(384) void mrf_solve_kernel(
    const float* __restrict__ unary, const float* __restrict__ A,
    float* __restrict__ msgbuf, unsigned short* __restrict__ ptrbuf,
    const int* __restrict__ parent, const int* __restrict__ childStart,
    const int* __restrict__ childList, const int* __restrict__ levStart,
    const int* __restrict__ levNodes, const float* __restrict__ w_edge,
    int* __restrict__ labels, const int* __restrict__ meta,
    int* __restrict__ ready)
{
  __shared__ float s_b[LBL];
  __shared__ int s_lab[NN];
  __shared__ int s_children[64];
  const int tid = threadIdx.x;
  int numLev = meta[0];
  if (numLev < 1) numLev = 1;
  if (numLev > NN) numLev = NN;

  bool didRoot = false;

  for (int p = blockIdx.x; p < NN; p += gridDim.x) {
    const int c = levNodes[NN - 1 - p] & (NN - 1);
    int cs = childStart[c], ce = childStart[c + 1];
    if (cs < 0) cs = 0;
    if (ce > NN - 1) ce = NN - 1;
    if (ce < cs) ce = cs;
    int deg = ce - cs;
    if (deg > 64) deg = 64;

    // ---- wait for children: relaxed read-through poll (no invalidates) ----
    if (deg > 0) {
      if (tid == 0) {
        long long guard = 0;
        while (__hip_atomic_load(&ready[c], __ATOMIC_RELAXED,
                                 __HIP_MEMORY_SCOPE_AGENT) < deg) {
          __builtin_amdgcn_s_sleep(4);
          if (++guard > 8000000LL) break;   // anti-hang escape (never expected)
        }
      }
      __syncthreads();
      if (tid < deg) s_children[tid] = childList[cs + tid] & (NN - 1);
    }
    __syncthreads();

    // ---- belief = unary + children msgs (reversed-Prim order, sc1 reads) ----
    if (tid < LBL) {
      float b = unary[(size_t)c * LBL + tid];
      for (int base2 = 0; base2 < deg; base2 += 8) {
        const int cnt = deg - base2 < 8 ? deg - base2 : 8;
        unsigned uv[8];
        #pragma unroll
        for (int q = 0; q < 8; ++q)
          if (q < cnt)
            uv[q] = __hip_atomic_load(
                (const unsigned*)&msgbuf[(size_t)s_children[base2 + q] * LBL + tid],
                __ATOMIC_RELAXED, __HIP_MEMORY_SCOPE_AGENT);
        #pragma unroll
        for (int q = 0; q < 8; ++q)
          if (q < cnt) b = __fadd_rn(b, __uint_as_float(uv[q]));
      }
      s_b[tid] = b;
    }
    __syncthreads();

    if (c != 0) {
      int bi = 0;
      if (tid < LBL) {
        const float w = w_edge[c];
        const float* __restrict__ Ac = A + tid;
        float bv = __fadd_rn(s_b[0], __fmul_rn(w, Ac[0]));
        int lc = 1;
        for (; lc < 7; ++lc) {
          const float s = __fadd_rn(s_b[lc], __fmul_rn(w, Ac[(size_t)lc * LBL]));
          if (s > bv) { bv = s; bi = lc; }
        }
        for (; lc + 8 <= LBL; lc += 8) {
          const float a0 = Ac[(size_t)(lc + 0) * LBL];
          const float a1 = Ac[(size_t)(lc + 1) * LBL];
          const float a2 = Ac[(size_t)(lc + 2) * LBL];
          const float a3 = Ac[(size_t)(lc + 3) * LBL];
          const float a4 = Ac[(size_t)(lc + 4) * LBL];
          const float a5 = Ac[(size_t)(lc + 5) * LBL];
          const float a6 = Ac[(size_t)(lc + 6) * LBL];
          const float a7 = Ac[(size_t)(lc + 7) * LBL];
          const float s0 = __fadd_rn(s_b[lc + 0], __fmul_rn(w, a0));
          const float s1 = __fadd_rn(s_b[lc + 1], __fmul_rn(w, a1));
          const float s2 = __fadd_rn(s_b[lc + 2], __fmul_rn(w, a2));
          const float s3 = __fadd_rn(s_b[lc + 3], __fmul_rn(w, a3));
          const float s4 = __fadd_rn(s_b[lc + 4], __fmul_rn(w, a4));
          const float s5 = __fadd_rn(s_b[lc + 5], __fmul_rn(w, a5));
          const float s6 = __fadd_rn(s_b[lc + 6], __fmul_rn(w, a6));
          const float s7 = __fadd_rn(s_b[lc + 7], __fmul_rn(w, a7));
          if (s0 > bv) { bv = s0; bi = lc + 0; }
          if (s1 > bv) { bv = s1; bi = lc + 1; }
          if (s2 > bv) { bv = s2; bi = lc + 2; }
          if (s3 > bv) { bv = s3; bi = lc + 3; }
          if (s4 > bv) { bv = s4; bi = lc + 4; }
          if (s5 > bv) { bv = s5; bi = lc + 5; }
          if (s6 > bv) { bv = s6; bi = lc + 6; }
          if (s7 > bv) { bv = s7; bi = lc + 7; }
        }
        // msg: write-through store (lands in L3, visible to relaxed readers)
        __hip_atomic_store((unsigned*)&msgbuf[(size_t)c * LBL + tid],
                           __float_as_uint(bv),
                           __ATOMIC_RELAXED, __HIP_MEMORY_SCOPE_AGENT);
      }
      // ptr: write u16 pairs as one aligned u32 sc1 store (stride PSTRIDE=344)
      const int nbi = __shfl_down(bi, 1);   // uniform: all 384 threads execute
      if (tid < LBL && (tid & 1) == 0) {
        const unsigned pk = ((unsigned)bi & 0xFFFFu) | (((unsigned)nbi & 0xFFFFu) << 16);
        __hip_atomic_store((unsigned*)(ptrbuf + (size_t)c * PSTRIDE + tid), pk,
                           __ATOMIC_RELAXED, __HIP_MEMORY_SCOPE_AGENT);
      }
      __syncthreads();
      if (tid == 0)
        __hip_atomic_fetch_add(&ready[parent[c] & (NN - 1)], 1,
                               __ATOMIC_RELEASE, __HIP_MEMORY_SCOPE_AGENT);
    } else {
      if (tid == 0) {
        float bv = s_b[0]; int bi = 0;
        for (int l = 1; l < LBL; ++l)
          if (s_b[l] > bv) { bv = s_b[l]; bi = l; }
        labels[0] = bi;
        s_lab[0] = bi;
      }
      __syncthreads();
      didRoot = true;   // all other nodes transitively complete
    }
  }

  // -------- downward backtracking (the block that finished the root) --------
  if (!didRoot) return;
  __syncthreads();
  for (int lev = 1; lev < numLev; ++lev) {
    int ls = levStart[lev], le = levStart[lev + 1];
    if (ls < 0) ls = 0;
    if (le > NN) le = NN;
    for (int idx = ls + tid; idx < le; idx += 384) {
      const int c = levNodes[idx] & (NN - 1);
      int pl = s_lab[parent[c] & (NN - 1)];
      if (pl < 0) pl = 0;
      if (pl >= LBL) pl = LBL - 1;
      const unsigned pk = __hip_atomic_load(
          (const unsigned*)(ptrbuf + (size_t)c * PSTRIDE + (pl & ~1)),
          __ATOMIC_RELAXED, __HIP_MEMORY_SCOPE_AGENT);
      const int lab = (pl & 1) ? (int)(pk >> 16) : (int)(pk & 0xFFFFu);
      s_lab[c] = lab;
      labels[c] = lab;
    }
    __syncthreads();
  }
}

// ---------------------------------------------------------------------------
// Kernel 4: output fill (2*onehot - 1) * 1e5 (overwrites all of d_out)
// ---------------------------------------------------------------------------
__global__ void mrf_out_kernel(const int* __restrict__ labels, float* __restrict__ out)
{
  const int id = blockIdx.x * blockDim.x + threadIdx.x;
  if (id >= NN * LBL) return;
  const int c = id / LBL;
  const int l = id - c * LBL;
  out[id] = (l == labels[c]) ? 100000.0f : -100000.0f;
}

extern "C" void kernel_launch(void* const* d_in, const int* in_sizes, int n_in,
                              void* d_out, int out_size, void* d_ws, size_t ws_size,
                              hipStream_t stream)
{
  (void)in_sizes; (void)n_in; (void)out_size; (void)ws_size;
  const float* unary = (const float*)d_in[0];
  const float* dist  = (const float*)d_in[1];
  const float* A     = (const float*)d_in[2];
  float* out = (float*)d_out;

  char* ws = (char*)d_ws;
  size_t off = 0;
  auto take = [&](size_t bytes) -> void* {
    void* p = (void*)(ws + off);
    off += (bytes + 255) & ~(size_t)255;
    return p;
  };
  float* msgbuf = out;   // aliases d_out; fully overwritten by mrf_out_kernel
  unsigned short* ptrbuf = (unsigned short*)take((size_t)NN * PSTRIDE * sizeof(unsigned short));
  int*      comp       = (int*)     take(NN * sizeof(int));
  u64*      minE       = (u64*)     take(NN * sizeof(u64));
  int*      hook       = (int*)     take(NN * sizeof(int));
  int*      eu         = (int*)     take(NN * sizeof(int));
  int*      ev         = (int*)     take(NN * sizeof(int));
  unsigned* ew         = (unsigned*)take(NN * sizeof(unsigned));
  int*      counters   = (int*)     take(256);
  int*      parent     = (int*)     take(NN * sizeof(int));
  int*      childStart = (int*)     take((NN + 1) * sizeof(int));
  int*      childList  = (int*)     take(NN * sizeof(int));
  int*      levStart   = (int*)     take((NN + 1) * sizeof(int));
  int*      levNodes   = (int*)     take(NN * sizeof(int));
  int*      labels     = (int*)     take(NN * sizeof(int));
  int*      meta       = (int*)     take(256);
  float*    w_edge     = (float*)   take(NN * sizeof(float));
  int*      ready      = (int*)     take(NN * sizeof(int));
  u64*      adjList    = (u64*)     take((size_t)2 * NN * sizeof(u64));

  {
    void* args[] = {
      (void*)&dist, (void*)&comp, (void*)&minE, (void*)&hook,
      (void*)&eu, (void*)&ev, (void*)&ew, (void*)&counters
    };
    hipLaunchCooperativeKernel((void*)mrf_boruvka_kernel, dim3(256), dim3(1024),
                               args, 0, stream);
  }

  hipLaunchKernelGGL(mrf_root_kernel, dim3(1), dim3(1024), 0, stream,
                     dist, eu, ev, ew, parent, childStart, childList,
                     levStart, levNodes, meta, w_edge, adjList, ready);

  {
    void* args[] = {
      (void*)&unary, (void*)&A, (void*)&msgbuf, (void*)&ptrbuf,
      (void*)&parent, (void*)&childStart, (void*)&childList,
      (void*)&levStart, (void*)&levNodes, (void*)&w_edge,
      (void*)&labels, (void*)&meta, (void*)&ready
    };
    hipLaunchCooperativeKernel((void*)mrf_solve_kernel, dim3(256), dim3(384),
                               args, 0, stream);
  }

  const int total = NN * LBL;
  hipLaunchKernelGGL(mrf_out_kernel, dim3((total + 255) / 256), dim3(256), 0, stream,
                     labels, out);
}

// Round 6
// 1424.462 us; speedup vs baseline: 4.4844x; 1.8089x over previous
//
#include <hip/hip_runtime.h>
#include <hip/hip_cooperative_groups.h>
#include <math.h>

namespace cg = cooperative_groups;
typedef unsigned long long u64;

#define NN 4096
#define LBL 343
#define PSTRIDE 344   // ptrbuf row stride (u16), even => aligned u32 pair stores
#define U64MAX 0xFFFFFFFFFFFFFFFFull
#define MST_ROUNDS 12 // components at least halve per round: 2^12 = 4096

// ---------------------------------------------------------------------------
// MST init: identity components, both minE parity buffers = MAX, counters.
// counters[0],[1] = root-count parity slots; counters[2] = edge cursor.
// ---------------------------------------------------------------------------
__global__ void mrf_mst_init_kernel(int* __restrict__ compA,
                                    u64* __restrict__ minEa, u64* __restrict__ minEb,
                                    int* __restrict__ counters)
{
  const int i = blockIdx.x * blockDim.x + threadIdx.x;
  if (i < NN) { compA[i] = i; minEa[i] = U64MAX; minEb[i] = U64MAX; }
  if (i == 0) { counters[0] = NN; counters[1] = NN; counters[2] = 0; }
}

// ---------------------------------------------------------------------------
// Boruvka phase 1 (per round): per-row min outgoing edge (one wave per row,
// 2 rows per wave), per-block LDS dedupe, then atomicMin into minE[comp].
// Kernel boundary replaces grid.sync (free coherence, no L2-invalidate storm).
// Early-exit path still resets this round's counter slot => no zombie rounds.
// ---------------------------------------------------------------------------
__global__ __launch_bounds__(1024) void mrf_scan_kernel(
    const float* __restrict__ dist, const int* __restrict__ compR,
    u64* __restrict__ minE, int* __restrict__ counters, int round)
{
  __shared__ int s_cc[32];
  __shared__ u64 s_cv[32];

  if (blockIdx.x == 0 && threadIdx.x == 0) counters[round & 1] = 0;
  if (round > 0 && counters[(round - 1) & 1] <= 1) return;

  const int wv   = (blockIdx.x * 1024 + threadIdx.x) >> 6;  // 0..2047
  const int lane = threadIdx.x & 63;
  const int wib  = threadIdx.x >> 6;                        // wave in block

  for (int half = 0; half < 2; ++half) {
    const int i = wv + half * 2048;
    const int ci = compR[i];
    const float4* rowp = (const float4*)(dist + (size_t)i * NN);
    const int4* cp = (const int4*)compR;
    u64 best = U64MAX;
    #pragma unroll 4
    for (int k = 0; k < 16; ++k) {
      const int q = k * 64 + lane;
      const float4 dv = rowp[q];
      const int4 cv = cp[q];
      const int j0 = q * 4;
      if (cv.x != ci) { const u64 p = ((u64)__float_as_uint(dv.x) << 24) | ((u64)i << 12) | (u64)(j0    ); best = best < p ? best : p; }
      if (cv.y != ci) { const u64 p = ((u64)__float_as_uint(dv.y) << 24) | ((u64)i << 12) | (u64)(j0 + 1); best = best < p ? best : p; }
      if (cv.z != ci) { const u64 p = ((u64)__float_as_uint(dv.z) << 24) | ((u64)i << 12) | (u64)(j0 + 2); best = best < p ? best : p; }
      if (cv.w != ci) { const u64 p = ((u64)__float_as_uint(dv.w) << 24) | ((u64)i << 12) | (u64)(j0 + 3); best = best < p ? best : p; }
    }
    #pragma unroll
    for (int sh = 32; sh >= 1; sh >>= 1) {
      const u64 o = __shfl_down(best, sh);
      best = best < o ? best : o;
    }
    if (lane == 0) {
      s_cc[wib * 2 + half] = (best == U64MAX) ? -1 : ci;
      s_cv[wib * 2 + half] = best;
    }
  }
  __syncthreads();
  if (threadIdx.x == 0) {
    // serial dedupe of 32 candidates -> <= #distinct-components atomics
    for (int a = 0; a < 32; ++a) {
      const int c = s_cc[a];
      if (c < 0) continue;
      bool dup = false;
      for (int b2 = 0; b2 < a; ++b2) if (s_cc[b2] == c) { dup = true; break; }
      if (dup) continue;
      u64 b = s_cv[a];
      for (int b2 = a + 1; b2 < 32; ++b2)
        if (s_cc[b2] == c && s_cv[b2] < b) b = s_cv[b2];
      atomicMin(&minE[c & (NN - 1)], b);
    }
  }
}

// ---------------------------------------------------------------------------
// Boruvka phases 2+3 fused: every node functionally recomputes the hook
// decision chain from (minE, compR) and chases to its final root.
// Mutual 2-cycles break at the smaller root id. Pre-round roots record their
// hook edge (exactly one edge per merge; NN-1 total over all rounds).
// Also resets the OTHER minE parity buffer for the next round.
// ---------------------------------------------------------------------------
__global__ __launch_bounds__(1024) void mrf_hook_kernel(
    const int* __restrict__ compR, int* __restrict__ compW,
    const u64* __restrict__ minE, u64* __restrict__ minEnext,
    int* __restrict__ eu, int* __restrict__ ev, unsigned* __restrict__ ew,
    int* __restrict__ counters, int round)
{
  if (round > 0 && counters[(round - 1) & 1] <= 1) return;
  const int i = blockIdx.x * 1024 + threadIdx.x;
  if (i >= NN) return;
  minEnext[i] = U64MAX;

  const int r0 = compR[i];
  int cur = r0;
  for (int guard = 0; guard < NN + 2; ++guard) {
    const u64 e = minE[cur];
    if (e == U64MAX) break;                      // no outgoing: final root
    const int v = (int)(e & 0xFFF);
    const int t = compR[v];
    if (t == cur) break;                         // safety (never in valid round)
    const u64 te = minE[t];
    if (te != U64MAX) {
      const int tv = (int)(te & 0xFFF);
      if (compR[tv] == cur && cur < t) break;    // mutual pair: cur wins
    }
    cur = t;
  }
  compW[i] = cur;
  if (cur == i) atomicAdd(&counters[round & 1], 1);

  if (r0 == i) {   // pre-round root: record my hook edge if I hooked
    const u64 e = minE[i];
    if (e != U64MAX) {
      const int v = (int)(e & 0xFFF);
      const int u = (int)((e >> 12) & 0xFFF);
      const unsigned wb = (unsigned)(e >> 24);
      const int t = compR[v];
      bool mutual = false;
      const u64 te = minE[t];
      if (te != U64MAX) {
        const int tv = (int)(te & 0xFFF);
        mutual = (compR[tv] == i);
      }
      if (!(mutual && i < t)) {
        const int slot = atomicAdd(&counters[2], 1);
        if (slot < NN) { eu[slot] = u; ev[slot] = v; ew[slot] = wb; }
      }
    }
  }
}

// ---------------------------------------------------------------------------
// block-wide exclusive scan over 4096 LDS ints (1024 threads, 4/thread)
// ---------------------------------------------------------------------------
__device__ __forceinline__ void scan4096(int* arr, int* tmp16, int tid)
{
  __syncthreads();
  const int base = tid * 4;
  const int c0 = arr[base], c1 = arr[base + 1], c2 = arr[base + 2], c3 = arr[base + 3];
  const int lsum = c0 + c1 + c2 + c3;
  const int lane = tid & 63, wid = tid >> 6;
  int incl = lsum;
  #pragma unroll
  for (int o = 1; o < 64; o <<= 1) {
    const int t = __shfl_up(incl, o);
    if (lane >= o) incl += t;
  }
  if (lane == 63) tmp16[wid] = incl;
  __syncthreads();
  if (tid == 0) {
    int run = 0;
    for (int w = 0; w < 16; ++w) { const int t = tmp16[w]; tmp16[w] = run; run += t; }
  }
  __syncthreads();
  const int excl = tmp16[wid] + incl - lsum;
  arr[base]     = excl;
  arr[base + 1] = excl + c0;
  arr[base + 2] = excl + c0 + c1;
  arr[base + 3] = excl + c0 + c1 + c2;
  __syncthreads();
}

// ---------------------------------------------------------------------------
// Kernel 2 (single block): root MST at 0, child lists desc-(wbits,idx)
// (== reversed Prim order), level buckets, w_edge, zero ready[].
// ---------------------------------------------------------------------------
__global__ __launch_bounds__(1024) void mrf_root_kernel(
    const float* __restrict__ dist,
    const int* __restrict__ eu, const int* __restrict__ ev, const unsigned* __restrict__ ew,
    int* __restrict__ parent_g, int* __restrict__ childStart, int* __restrict__ childList,
    int* __restrict__ levStart, int* __restrict__ levNodes,
    int* __restrict__ meta, float* __restrict__ w_edge,
    u64* __restrict__ adjList, int* __restrict__ ready)
{
  __shared__ int s_deg[NN];
  __shared__ int s_start[NN];
  __shared__ int s_cur[NN];
  __shared__ int s_parent[NN];
  __shared__ unsigned short s_dep[NN];
  __shared__ unsigned short s_fr[2][NN];
  __shared__ int s_tmp16[16];
  __shared__ int s_fcnt, s_nf;

  const int tid = threadIdx.x;

  for (int j = tid; j < NN; j += 1024) ready[j] = 0;   // fresh every call

  // ---- adjacency ----
  for (int j = tid; j < NN; j += 1024) s_deg[j] = 0;
  __syncthreads();
  for (int e = tid; e < NN - 1; e += 1024) {
    atomicAdd(&s_deg[eu[e] & (NN - 1)], 1);
    atomicAdd(&s_deg[ev[e] & (NN - 1)], 1);
  }
  __syncthreads();
  for (int j = tid; j < NN; j += 1024) s_start[j] = s_deg[j];
  scan4096(s_start, s_tmp16, tid);
  for (int j = tid; j < NN; j += 1024) s_cur[j] = s_start[j];
  __syncthreads();
  for (int e = tid; e < NN - 1; e += 1024) {
    const int u = eu[e] & (NN - 1), v = ev[e] & (NN - 1);
    const u64 wb = (u64)ew[e];
    const int p1 = atomicAdd(&s_cur[u], 1);
    adjList[p1] = (wb << 12) | (u64)v;
    const int p2 = atomicAdd(&s_cur[v], 1);
    adjList[p2] = (wb << 12) | (u64)u;
  }
  __syncthreads();

  // ---- BFS from node 0 ----
  for (int j = tid; j < NN; j += 1024) { s_parent[j] = 0; s_dep[j] = 0; }
  if (tid == 0) { s_fcnt = 1; s_nf = 0; s_fr[0][0] = 0; }
  __syncthreads();
  int cur = 0, lev = 0;
  while (true) {
    const int fcnt = s_fcnt;
    if (fcnt == 0) break;
    for (int idx = tid; idx < fcnt; idx += 1024) {
      const int x = s_fr[cur][idx];
      const int st = s_start[x], dg = s_deg[x];
      for (int a = 0; a < dg; ++a) {
        const u64 ent = adjList[st + a];
        const int nb = (int)(ent & 0xFFF);
        if (nb != s_parent[x] || x == 0) {     // tree: each nb discovered once
          s_parent[nb] = x;
          s_dep[nb] = (unsigned short)(lev + 1);
          const int slot = atomicAdd(&s_nf, 1);
          s_fr[1 - cur][slot] = (unsigned short)nb;
        }
      }
    }
    __syncthreads();
    if (tid == 0) { s_fcnt = s_nf; s_nf = 0; }
    ++lev;
    cur ^= 1;
    __syncthreads();
  }
  const int numLev = lev;
  if (tid == 0) { s_parent[0] = 0; meta[0] = numLev; }
  __syncthreads();

  // ---- childStart ----
  int* s_cs2 = (int*)s_fr;
  for (int j = tid; j < NN; j += 1024) s_cs2[j] = s_deg[j] - (j != 0 ? 1 : 0);
  scan4096(s_cs2, s_tmp16, tid);
  for (int j = tid; j < NN; j += 1024) childStart[j] = s_cs2[j];
  if (tid == 0) childStart[NN] = NN - 1;
  __syncthreads();

  // ---- children sorted descending by (wbits, idx) ----
  for (int p = tid; p < NN; p += 1024) {
    const int st = s_start[p], dg = s_deg[p], cs = s_cs2[p];
    const int par = s_parent[p];
    u64 buf[16];
    int m = 0;
    for (int a = 0; a < dg; ++a) {
      const u64 ent = adjList[st + a];
      const int nb = (int)(ent & 0xFFF);
      if (p != 0 && nb == par) continue;
      if (m < 16) {
        int q = m;
        while (q > 0 && buf[q - 1] < ent) { buf[q] = buf[q - 1]; --q; }
        buf[q] = ent;
        ++m;
      } else {
        childList[cs + m] = nb;
        ++m;
      }
    }
    const int lim = m < 16 ? m : 16;
    for (int k = 0; k < lim; ++k) childList[cs + k] = (int)(buf[k] & 0xFFF);
  }

  // ---- level buckets ----
  for (int j = tid; j < NN; j += 1024) s_cur[j] = 0;
  __syncthreads();
  for (int j = tid; j < NN; j += 1024) atomicAdd(&s_cur[s_dep[j]], 1);
  scan4096(s_cur, s_tmp16, tid);
  for (int j = tid; j < NN; j += 1024) { levStart[j] = s_cur[j]; s_start[j] = s_cur[j]; }
  if (tid == 0) levStart[NN] = NN;
  __syncthreads();
  for (int j = tid; j < NN; j += 1024) {
    const int pos = atomicAdd(&s_start[s_dep[j]], 1);
    levNodes[pos] = j;
  }

  // ---- outputs ----
  for (int j = tid; j < NN; j += 1024) {
    parent_g[j] = s_parent[j];
    w_edge[j] = (j == 0) ? 0.0f
                         : expf(-dist[(size_t)j * NN + s_parent[j]] / 0.18f);
  }
}

// ---------------------------------------------------------------------------
// Kernel 3 (cooperative, dataflow via write-through L3 atomics):
// - poll ready[c] with RELAXED agent loads (read-through, NO invalidate)
// - msg/ptr cross-block data moved ONLY via relaxed agent atomics (sc1)
// - producer: relaxed sc1 stores, then one RELEASE agent fetch_add
// => no acquire fences, no L2 invalidation: A stays cache-resident.
// ---------------------------------------------------------------------------
__global__ __launch_bounds__(384) void mrf_solve_kernel(
    const float* __restrict__ unary, const float* __restrict__ A,
    float* __restrict__ msgbuf, unsigned short* __restrict__ ptrbuf,
    const int* __restrict__ parent, const int* __restrict__ childStart,
    const int* __restrict__ childList, const int* __restrict__ levStart,
    const int* __restrict__ levNodes, const float* __restrict__ w_edge,
    int* __restrict__ labels, const int* __restrict__ meta,
    int* __restrict__ ready)
{
  __shared__ float s_b[LBL];
  __shared__ int s_lab[NN];
  __shared__ int s_children[64];
  const int tid = threadIdx.x;
  int numLev = meta[0];
  if (numLev < 1) numLev = 1;
  if (numLev > NN) numLev = NN;

  bool didRoot = false;

  for (int p = blockIdx.x; p < NN; p += gridDim.x) {
    const int c = levNodes[NN - 1 - p] & (NN - 1);
    int cs = childStart[c], ce = childStart[c + 1];
    if (cs < 0) cs = 0;
    if (ce > NN - 1) ce = NN - 1;
    if (ce < cs) ce = cs;
    int deg = ce - cs;
    if (deg > 64) deg = 64;

    // ---- wait for children: relaxed read-through poll (no invalidates) ----
    if (deg > 0) {
      if (tid == 0) {
        long long guard = 0;
        while (__hip_atomic_load(&ready[c], __ATOMIC_RELAXED,
                                 __HIP_MEMORY_SCOPE_AGENT) < deg) {
          __builtin_amdgcn_s_sleep(4);
          if (++guard > 8000000LL) break;   // anti-hang escape (never expected)
        }
      }
      __syncthreads();
      if (tid < deg) s_children[tid] = childList[cs + tid] & (NN - 1);
    }
    __syncthreads();

    // ---- belief = unary + children msgs (reversed-Prim order, sc1 reads) ----
    if (tid < LBL) {
      float b = unary[(size_t)c * LBL + tid];
      for (int base2 = 0; base2 < deg; base2 += 8) {
        const int cnt = deg - base2 < 8 ? deg - base2 : 8;
        unsigned uv[8];
        #pragma unroll
        for (int q = 0; q < 8; ++q)
          if (q < cnt)
            uv[q] = __hip_atomic_load(
                (const unsigned*)&msgbuf[(size_t)s_children[base2 + q] * LBL + tid],
                __ATOMIC_RELAXED, __HIP_MEMORY_SCOPE_AGENT);
        #pragma unroll
        for (int q = 0; q < 8; ++q)
          if (q < cnt) b = __fadd_rn(b, __uint_as_float(uv[q]));
      }
      s_b[tid] = b;
    }
    __syncthreads();

    if (c != 0) {
      int bi = 0;
      if (tid < LBL) {
        const float w = w_edge[c];
        const float* __restrict__ Ac = A + tid;
        float bv = __fadd_rn(s_b[0], __fmul_rn(w, Ac[0]));
        int lc = 1;
        for (; lc < 7; ++lc) {
          const float s = __fadd_rn(s_b[lc], __fmul_rn(w, Ac[(size_t)lc * LBL]));
          if (s > bv) { bv = s; bi = lc; }
        }
        for (; lc + 8 <= LBL; lc += 8) {
          const float a0 = Ac[(size_t)(lc + 0) * LBL];
          const float a1 = Ac[(size_t)(lc + 1) * LBL];
          const float a2 = Ac[(size_t)(lc + 2) * LBL];
          const float a3 = Ac[(size_t)(lc + 3) * LBL];
          const float a4 = Ac[(size_t)(lc + 4) * LBL];
          const float a5 = Ac[(size_t)(lc + 5) * LBL];
          const float a6 = Ac[(size_t)(lc + 6) * LBL];
          const float a7 = Ac[(size_t)(lc + 7) * LBL];
          const float s0 = __fadd_rn(s_b[lc + 0], __fmul_rn(w, a0));
          const float s1 = __fadd_rn(s_b[lc + 1], __fmul_rn(w, a1));
          const float s2 = __fadd_rn(s_b[lc + 2], __fmul_rn(w, a2));
          const float s3 = __fadd_rn(s_b[lc + 3], __fmul_rn(w, a3));
          const float s4 = __fadd_rn(s_b[lc + 4], __fmul_rn(w, a4));
          const float s5 = __fadd_rn(s_b[lc + 5], __fmul_rn(w, a5));
          const float s6 = __fadd_rn(s_b[lc + 6], __fmul_rn(w, a6));
          const float s7 = __fadd_rn(s_b[lc + 7], __fmul_rn(w, a7));
          if (s0 > bv) { bv = s0; bi = lc + 0; }
          if (s1 > bv) { bv = s1; bi = lc + 1; }
          if (s2 > bv) { bv = s2; bi = lc + 2; }
          if (s3 > bv) { bv = s3; bi = lc + 3; }
          if (s4 > bv) { bv = s4; bi = lc + 4; }
          if (s5 > bv) { bv = s5; bi = lc + 5; }
          if (s6 > bv) { bv = s6; bi = lc + 6; }
          if (s7 > bv) { bv = s7; bi = lc + 7; }
        }
        // msg: write-through store (lands in L3, visible to relaxed readers)
        __hip_atomic_store((unsigned*)&msgbuf[(size_t)c * LBL + tid],
                           __float_as_uint(bv),
                           __ATOMIC_RELAXED, __HIP_MEMORY_SCOPE_AGENT);
      }
      // ptr: write u16 pairs as one aligned u32 sc1 store (stride PSTRIDE=344)
      const int nbi = __shfl_down(bi, 1);   // uniform: all 384 threads execute
      if (tid < LBL && (tid & 1) == 0) {
        const unsigned pk = ((unsigned)bi & 0xFFFFu) | (((unsigned)nbi & 0xFFFFu) << 16);
        __hip_atomic_store((unsigned*)(ptrbuf + (size_t)c * PSTRIDE + tid), pk,
                           __ATOMIC_RELAXED, __HIP_MEMORY_SCOPE_AGENT);
      }
      __syncthreads();
      if (tid == 0)
        __hip_atomic_fetch_add(&ready[parent[c] & (NN - 1)], 1,
                               __ATOMIC_RELEASE, __HIP_MEMORY_SCOPE_AGENT);
    } else {
      if (tid == 0) {
        float bv = s_b[0]; int bi = 0;
        for (int l = 1; l < LBL; ++l)
          if (s_b[l] > bv) { bv = s_b[l]; bi = l; }
        labels[0] = bi;
        s_lab[0] = bi;
      }
      __syncthreads();
      didRoot = true;   // all other nodes transitively complete
    }
  }

  // -------- downward backtracking (the block that finished the root) --------
  if (!didRoot) return;
  __syncthreads();
  for (int lev = 1; lev < numLev; ++lev) {
    int ls = levStart[lev], le = levStart[lev + 1];
    if (ls < 0) ls = 0;
    if (le > NN) le = NN;
    for (int idx = ls + tid; idx < le; idx += 384) {
      const int c = levNodes[idx] & (NN - 1);
      int pl = s_lab[parent[c] & (NN - 1)];
      if (pl < 0) pl = 0;
      if (pl >= LBL) pl = LBL - 1;
      const unsigned pk = __hip_atomic_load(
          (const unsigned*)(ptrbuf + (size_t)c * PSTRIDE + (pl & ~1)),
          __ATOMIC_RELAXED, __HIP_MEMORY_SCOPE_AGENT);
      const int lab = (pl & 1) ? (int)(pk >> 16) : (int)(pk & 0xFFFFu);
      s_lab[c] = lab;
      labels[c] = lab;
    }
    __syncthreads();
  }
}

// ---------------------------------------------------------------------------
// Kernel 4: output fill (2*onehot - 1) * 1e5 (overwrites all of d_out)
// ---------------------------------------------------------------------------
__global__ void mrf_out_kernel(const int* __restrict__ labels, float* __restrict__ out)
{
  const int id = blockIdx.x * blockDim.x + threadIdx.x;
  if (id >= NN * LBL) return;
  const int c = id / LBL;
  const int l = id - c * LBL;
  out[id] = (l == labels[c]) ? 100000.0f : -100000.0f;
}

extern "C" void kernel_launch(void* const* d_in, const int* in_sizes, int n_in,
                              void* d_out, int out_size, void* d_ws, size_t ws_size,
                              hipStream_t stream)
{
  (void)in_sizes; (void)n_in; (void)out_size; (void)ws_size;
  const float* unary = (const float*)d_in[0];
  const float* dist  = (const float*)d_in[1];
  const float* A     = (const float*)d_in[2];
  float* out = (float*)d_out;

  char* ws = (char*)d_ws;
  size_t off = 0;
  auto take = [&](size_t bytes) -> void* {
    void* p = (void*)(ws + off);
    off += (bytes + 255) & ~(size_t)255;
    return p;
  };
  float* msgbuf = out;   // aliases d_out; fully overwritten by mrf_out_kernel
  unsigned short* ptrbuf = (unsigned short*)take((size_t)NN * PSTRIDE * sizeof(unsigned short));
  int*      compA      = (int*)     take(NN * sizeof(int));
  int*      compB      = (int*)     take(NN * sizeof(int));
  u64*      minEa      = (u64*)     take(NN * sizeof(u64));
  u64*      minEb      = (u64*)     take(NN * sizeof(u64));
  int*      eu         = (int*)     take(NN * sizeof(int));
  int*      ev         = (int*)     take(NN * sizeof(int));
  unsigned* ew         = (unsigned*)take(NN * sizeof(unsigned));
  int*      counters   = (int*)     take(256);
  int*      parent     = (int*)     take(NN * sizeof(int));
  int*      childStart = (int*)     take((NN + 1) * sizeof(int));
  int*      childList  = (int*)     take(NN * sizeof(int));
  int*      levStart   = (int*)     take((NN + 1) * sizeof(int));
  int*      levNodes   = (int*)     take(NN * sizeof(int));
  int*      labels     = (int*)     take(NN * sizeof(int));
  int*      meta       = (int*)     take(256);
  float*    w_edge     = (float*)   take(NN * sizeof(float));
  int*      ready      = (int*)     take(NN * sizeof(int));
  u64*      adjList    = (u64*)     take((size_t)2 * NN * sizeof(u64));

  hipLaunchKernelGGL(mrf_mst_init_kernel, dim3(4), dim3(1024), 0, stream,
                     compA, minEa, minEb, counters);

  for (int r = 0; r < MST_ROUNDS; ++r) {
    const int* compR = (r & 1) ? compB : compA;
    int*       compW = (r & 1) ? compA : compB;
    u64*       mcur  = (r & 1) ? minEb : minEa;
    u64*       mnext = (r & 1) ? minEa : minEb;
    hipLaunchKernelGGL(mrf_scan_kernel, dim3(128), dim3(1024), 0, stream,
                       dist, compR, mcur, counters, r);
    hipLaunchKernelGGL(mrf_hook_kernel, dim3(4), dim3(1024), 0, stream,
                       compR, compW, mcur, mnext, eu, ev, ew, counters, r);
  }

  hipLaunchKernelGGL(mrf_root_kernel, dim3(1), dim3(1024), 0, stream,
                     dist, eu, ev, ew, parent, childStart, childList,
                     levStart, levNodes, meta, w_edge, adjList, ready);

  {
    void* args[] = {
      (void*)&unary, (void*)&A, (void*)&msgbuf, (void*)&ptrbuf,
      (void*)&parent, (void*)&childStart, (void*)&childList,
      (void*)&levStart, (void*)&levNodes, (void*)&w_edge,
      (void*)&labels, (void*)&meta, (void*)&ready
    };
    hipLaunchCooperativeKernel((void*)mrf_solve_kernel, dim3(256), dim3(384),
                               args, 0, stream);
  }

  const int total = NN * LBL;
  hipLaunchKernelGGL(mrf_out_kernel, dim3((total + 255) / 256), dim3(256), 0, stream,
                     labels, out);
}

// Round 7
// 1405.275 us; speedup vs baseline: 4.5457x; 1.0137x over previous
//
#include <hip/hip_runtime.h>
#include <hip/hip_cooperative_groups.h>
#include <math.h>

namespace cg = cooperative_groups;
typedef unsigned long long u64;

#define NN 4096
#define LBL 343
#define PSTRIDE 344   // ptrbuf row stride (u16), even => aligned u32 pair stores
#define U64MAX 0xFFFFFFFFFFFFFFFFull
#define MST_ROUNDS 12 // components at least halve per round: 2^12 = 4096

// ---------------------------------------------------------------------------
// MST init: identity components, both minE parity buffers = MAX, counters.
// counters[0],[1] = root-count parity slots; counters[2] = edge cursor.
// ---------------------------------------------------------------------------
__global__ void mrf_mst_init_kernel(int* __restrict__ compA,
                                    u64* __restrict__ minEa, u64* __restrict__ minEb,
                                    int* __restrict__ counters)
{
  const int i = blockIdx.x * blockDim.x + threadIdx.x;
  if (i < NN) { compA[i] = i; minEa[i] = U64MAX; minEb[i] = U64MAX; }
  if (i == 0) { counters[0] = NN; counters[1] = NN; counters[2] = 0; }
}

// ---------------------------------------------------------------------------
// Boruvka phase 1 (per round): per-row min outgoing edge (one wave per row,
// 2 rows per wave), per-block LDS dedupe, then atomicMin into minE[comp].
// ---------------------------------------------------------------------------
__global__ __launch_bounds__(1024) void mrf_scan_kernel(
    const float* __restrict__ dist, const int* __restrict__ compR,
    u64* __restrict__ minE, int* __restrict__ counters, int round)
{
  __shared__ int s_cc[32];
  __shared__ u64 s_cv[32];

  if (blockIdx.x == 0 && threadIdx.x == 0) counters[round & 1] = 0;
  if (round > 0 && counters[(round - 1) & 1] <= 1) return;

  const int wv   = (blockIdx.x * 1024 + threadIdx.x) >> 6;  // 0..2047
  const int lane = threadIdx.x & 63;
  const int wib  = threadIdx.x >> 6;                        // wave in block

  for (int half = 0; half < 2; ++half) {
    const int i = wv + half * 2048;
    const int ci = compR[i];
    const float4* rowp = (const float4*)(dist + (size_t)i * NN);
    const int4* cp = (const int4*)compR;
    u64 best = U64MAX;
    #pragma unroll 4
    for (int k = 0; k < 16; ++k) {
      const int q = k * 64 + lane;
      const float4 dv = rowp[q];
      const int4 cv = cp[q];
      const int j0 = q * 4;
      if (cv.x != ci) { const u64 p = ((u64)__float_as_uint(dv.x) << 24) | ((u64)i << 12) | (u64)(j0    ); best = best < p ? best : p; }
      if (cv.y != ci) { const u64 p = ((u64)__float_as_uint(dv.y) << 24) | ((u64)i << 12) | (u64)(j0 + 1); best = best < p ? best : p; }
      if (cv.z != ci) { const u64 p = ((u64)__float_as_uint(dv.z) << 24) | ((u64)i << 12) | (u64)(j0 + 2); best = best < p ? best : p; }
      if (cv.w != ci) { const u64 p = ((u64)__float_as_uint(dv.w) << 24) | ((u64)i << 12) | (u64)(j0 + 3); best = best < p ? best : p; }
    }
    #pragma unroll
    for (int sh = 32; sh >= 1; sh >>= 1) {
      const u64 o = __shfl_down(best, sh);
      best = best < o ? best : o;
    }
    if (lane == 0) {
      s_cc[wib * 2 + half] = (best == U64MAX) ? -1 : ci;
      s_cv[wib * 2 + half] = best;
    }
  }
  __syncthreads();
  if (threadIdx.x == 0) {
    for (int a = 0; a < 32; ++a) {
      const int c = s_cc[a];
      if (c < 0) continue;
      bool dup = false;
      for (int b2 = 0; b2 < a; ++b2) if (s_cc[b2] == c) { dup = true; break; }
      if (dup) continue;
      u64 b = s_cv[a];
      for (int b2 = a + 1; b2 < 32; ++b2)
        if (s_cc[b2] == c && s_cv[b2] < b) b = s_cv[b2];
      atomicMin(&minE[c & (NN - 1)], b);
    }
  }
}

// ---------------------------------------------------------------------------
// Boruvka phases 2+3 fused (unchanged, passing).
// ---------------------------------------------------------------------------
__global__ __launch_bounds__(1024) void mrf_hook_kernel(
    const int* __restrict__ compR, int* __restrict__ compW,
    const u64* __restrict__ minE, u64* __restrict__ minEnext,
    int* __restrict__ eu, int* __restrict__ ev, unsigned* __restrict__ ew,
    int* __restrict__ counters, int round)
{
  if (round > 0 && counters[(round - 1) & 1] <= 1) return;
  const int i = blockIdx.x * 1024 + threadIdx.x;
  if (i >= NN) return;
  minEnext[i] = U64MAX;

  const int r0 = compR[i];
  int cur = r0;
  for (int guard = 0; guard < NN + 2; ++guard) {
    const u64 e = minE[cur];
    if (e == U64MAX) break;
    const int v = (int)(e & 0xFFF);
    const int t = compR[v];
    if (t == cur) break;
    const u64 te = minE[t];
    if (te != U64MAX) {
      const int tv = (int)(te & 0xFFF);
      if (compR[tv] == cur && cur < t) break;    // mutual pair: cur wins
    }
    cur = t;
  }
  compW[i] = cur;
  if (cur == i) atomicAdd(&counters[round & 1], 1);

  if (r0 == i) {
    const u64 e = minE[i];
    if (e != U64MAX) {
      const int v = (int)(e & 0xFFF);
      const int u = (int)((e >> 12) & 0xFFF);
      const unsigned wb = (unsigned)(e >> 24);
      const int t = compR[v];
      bool mutual = false;
      const u64 te = minE[t];
      if (te != U64MAX) {
        const int tv = (int)(te & 0xFFF);
        mutual = (compR[tv] == i);
      }
      if (!(mutual && i < t)) {
        const int slot = atomicAdd(&counters[2], 1);
        if (slot < NN) { eu[slot] = u; ev[slot] = v; ew[slot] = wb; }
      }
    }
  }
}

// ---------------------------------------------------------------------------
// block-wide exclusive scan over 4096 LDS ints (1024 threads, 4/thread)
// ---------------------------------------------------------------------------
__device__ __forceinline__ void scan4096(int* arr, int* tmp16, int tid)
{
  __syncthreads();
  const int base = tid * 4;
  const int c0 = arr[base], c1 = arr[base + 1], c2 = arr[base + 2], c3 = arr[base + 3];
  const int lsum = c0 + c1 + c2 + c3;
  const int lane = tid & 63, wid = tid >> 6;
  int incl = lsum;
  #pragma unroll
  for (int o = 1; o < 64; o <<= 1) {
    const int t = __shfl_up(incl, o);
    if (lane >= o) incl += t;
  }
  if (lane == 63) tmp16[wid] = incl;
  __syncthreads();
  if (tid == 0) {
    int run = 0;
    for (int w = 0; w < 16; ++w) { const int t = tmp16[w]; tmp16[w] = run; run += t; }
  }
  __syncthreads();
  const int excl = tmp16[wid] + incl - lsum;
  arr[base]     = excl;
  arr[base + 1] = excl + c0;
  arr[base + 2] = excl + c0 + c1;
  arr[base + 3] = excl + c0 + c1 + c2;
  __syncthreads();
}

// ---------------------------------------------------------------------------
// Kernel 2 (single block): root MST at 0, child lists desc-(wbits,idx)
// (== reversed Prim order), level buckets, carrier-segment list sorted by
// depth-of-last-node DESC (a provable topological order of segments),
// w_edge, zero ready[].
// ---------------------------------------------------------------------------
__global__ __launch_bounds__(1024) void mrf_root_kernel(
    const float* __restrict__ dist,
    const int* __restrict__ eu, const int* __restrict__ ev, const unsigned* __restrict__ ew,
    int* __restrict__ parent_g, int* __restrict__ childStart, int* __restrict__ childList,
    int* __restrict__ levStart, int* __restrict__ levNodes, int* __restrict__ segList,
    int* __restrict__ meta, float* __restrict__ w_edge,
    u64* __restrict__ adjList, int* __restrict__ ready)
{
  __shared__ int s_deg[NN];
  __shared__ int s_start[NN];
  __shared__ int s_cur[NN];
  __shared__ int s_parent[NN];
  __shared__ unsigned short s_dep[NN];
  __shared__ unsigned short s_fr[2][NN];
  __shared__ int s_tmp16[16];
  __shared__ int s_fcnt, s_nf;

  const int tid = threadIdx.x;

  for (int j = tid; j < NN; j += 1024) ready[j] = 0;   // fresh every call

  // ---- adjacency ----
  for (int j = tid; j < NN; j += 1024) s_deg[j] = 0;
  __syncthreads();
  for (int e = tid; e < NN - 1; e += 1024) {
    atomicAdd(&s_deg[eu[e] & (NN - 1)], 1);
    atomicAdd(&s_deg[ev[e] & (NN - 1)], 1);
  }
  __syncthreads();
  for (int j = tid; j < NN; j += 1024) s_start[j] = s_deg[j];
  scan4096(s_start, s_tmp16, tid);
  for (int j = tid; j < NN; j += 1024) s_cur[j] = s_start[j];
  __syncthreads();
  for (int e = tid; e < NN - 1; e += 1024) {
    const int u = eu[e] & (NN - 1), v = ev[e] & (NN - 1);
    const u64 wb = (u64)ew[e];
    const int p1 = atomicAdd(&s_cur[u], 1);
    adjList[p1] = (wb << 12) | (u64)v;
    const int p2 = atomicAdd(&s_cur[v], 1);
    adjList[p2] = (wb << 12) | (u64)u;
  }
  __syncthreads();

  // ---- BFS from node 0 ----
  for (int j = tid; j < NN; j += 1024) { s_parent[j] = 0; s_dep[j] = 0; }
  if (tid == 0) { s_fcnt = 1; s_nf = 0; s_fr[0][0] = 0; }
  __syncthreads();
  int cur = 0, lev = 0;
  while (true) {
    const int fcnt = s_fcnt;
    if (fcnt == 0) break;
    for (int idx = tid; idx < fcnt; idx += 1024) {
      const int x = s_fr[cur][idx];
      const int st = s_start[x], dg = s_deg[x];
      for (int a = 0; a < dg; ++a) {
        const u64 ent = adjList[st + a];
        const int nb = (int)(ent & 0xFFF);
        if (nb != s_parent[x] || x == 0) {
          s_parent[nb] = x;
          s_dep[nb] = (unsigned short)(lev + 1);
          const int slot = atomicAdd(&s_nf, 1);
          s_fr[1 - cur][slot] = (unsigned short)nb;
        }
      }
    }
    __syncthreads();
    if (tid == 0) { s_fcnt = s_nf; s_nf = 0; }
    ++lev;
    cur ^= 1;
    __syncthreads();
  }
  const int numLev = lev;
  if (tid == 0) { s_parent[0] = 0; meta[0] = numLev; }
  __syncthreads();

  // ---- childStart ----
  int* s_cs2 = (int*)s_fr;     // 4096 ints, overlays frontier memory
  for (int j = tid; j < NN; j += 1024) s_cs2[j] = s_deg[j] - (j != 0 ? 1 : 0);
  scan4096(s_cs2, s_tmp16, tid);
  for (int j = tid; j < NN; j += 1024) childStart[j] = s_cs2[j];
  if (tid == 0) childStart[NN] = NN - 1;
  __syncthreads();

  // ---- children sorted descending by (wbits, idx) ----
  for (int p = tid; p < NN; p += 1024) {
    const int st = s_start[p], dg = s_deg[p], cs = s_cs2[p];
    const int par = s_parent[p];
    u64 buf[16];
    int m = 0;
    for (int a = 0; a < dg; ++a) {
      const u64 ent = adjList[st + a];
      const int nb = (int)(ent & 0xFFF);
      if (p != 0 && nb == par) continue;
      if (m < 16) {
        int q = m;
        while (q > 0 && buf[q - 1] < ent) { buf[q] = buf[q - 1]; --q; }
        buf[q] = ent;
        ++m;
      } else {
        childList[cs + m] = nb;
        ++m;
      }
    }
    const int lim = m < 16 ? m : 16;
    for (int k = 0; k < lim; ++k) childList[cs + k] = (int)(buf[k] & 0xFFF);
  }

  // ---- level buckets ----
  for (int j = tid; j < NN; j += 1024) s_cur[j] = 0;
  __syncthreads();
  for (int j = tid; j < NN; j += 1024) atomicAdd(&s_cur[s_dep[j]], 1);
  scan4096(s_cur, s_tmp16, tid);
  for (int j = tid; j < NN; j += 1024) { levStart[j] = s_cur[j]; s_start[j] = s_cur[j]; }
  if (tid == 0) levStart[NN] = NN;
  __syncthreads();
  for (int j = tid; j < NN; j += 1024) {
    const int pos = atomicAdd(&s_start[s_dep[j]], 1);
    levNodes[pos] = j;
  }
  __syncthreads();

  // ---- carrier segments: one per leaf; key = depth of segment's LAST node.
  // Segment advances v -> parent(v) while v is the carrier (first child).
  // Sort segments by key DESC == topological order of the segment DAG.
  if (tid == 0) s_nf = 0;
  for (int j = tid; j < NN; j += 1024) s_cur[j] = 0;   // bucket counts
  __syncthreads();
  for (int j = tid; j < NN; j += 1024) {
    const int ce = (j == NN - 1) ? (NN - 1) : s_cs2[j + 1];
    int key = -1;
    if (ce - s_cs2[j] == 0) {          // leaf
      int c = j;
      while (c != 0) {
        const int par = s_parent[c];
        if (childList[s_cs2[par]] != c) break;   // c is not the carrier
        c = par;
      }
      key = s_dep[c];
      atomicAdd(&s_cur[numLev - 1 - key], 1);
      atomicAdd(&s_nf, 1);
    }
    s_deg[j] = key;                    // s_deg reused as per-leaf key store
  }
  scan4096(s_cur, s_tmp16, tid);
  for (int j = tid; j < NN; j += 1024) s_start[j] = s_cur[j];
  __syncthreads();
  for (int j = tid; j < NN; j += 1024) {
    const int key = s_deg[j];
    if (key >= 0) {
      const int pos = atomicAdd(&s_start[numLev - 1 - key], 1);
      segList[pos] = j;
    }
  }
  if (tid == 0) meta[1] = s_nf;

  // ---- outputs ----
  for (int j = tid; j < NN; j += 1024) {
    parent_g[j] = s_parent[j];
    w_edge[j] = (j == 0) ? 0.0f
                         : expf(-dist[(size_t)j * NN + s_parent[j]] / 0.18f);
  }
}

// ---------------------------------------------------------------------------
// Kernel 3 (cooperative, carrier-chain dataflow): each block walks whole
// segments leaf->...->branch. Along the chain the message stays local (no L3
// msg store, no release, no poll). Only non-carrier segment ends store+release;
// only branch nodes poll ready[p] >= deg-1. Belief order preserved: carrier is
// the FIRST child in desc-(weight,idx) order, so local msg seeds the sum.
// msgbuf aliases d_out (fully overwritten afterwards).
// ---------------------------------------------------------------------------
__global__ __launch_bounds__(384) void mrf_solve_kernel(
    const float* __restrict__ unary, const float* __restrict__ A,
    float* __restrict__ msgbuf, unsigned short* __restrict__ ptrbuf,
    const int* __restrict__ parent, const int* __restrict__ childStart,
    const int* __restrict__ childList, const int* __restrict__ levStart,
    const int* __restrict__ levNodes, const int* __restrict__ segList,
    const float* __restrict__ w_edge,
    int* __restrict__ labels, const int* __restrict__ meta,
    int* __restrict__ ready)
{
  __shared__ float s_b[LBL];
  __shared__ int s_lab[NN];
  const int tid = threadIdx.x;
  int numLev = meta[0];
  if (numLev < 1) numLev = 1;
  if (numLev > NN) numLev = NN;
  int numSegs = meta[1];
  if (numSegs < 1) numSegs = 1;
  if (numSegs > NN) numSegs = NN;

  bool didRoot = false;

  for (int sidx = blockIdx.x; sidx < numSegs && !didRoot; sidx += gridDim.x) {
    int v = segList[sidx] & (NN - 1);
    float b = (tid < LBL) ? unary[(size_t)v * LBL + tid] : 0.0f;  // leaf belief

    while (true) {
      if (tid < LBL) s_b[tid] = b;
      __syncthreads();

      if (v == 0) {
        if (tid == 0) {
          float bv = s_b[0]; int bi = 0;
          for (int l = 1; l < LBL; ++l)
            if (s_b[l] > bv) { bv = s_b[l]; bi = l; }
          labels[0] = bi;
          s_lab[0] = bi;
        }
        __syncthreads();
        didRoot = true;
        break;
      }

      // ---- message: argmax over lc of s_b[lc] + w*A[lc][tid] ----
      float bv = 0.0f; int bi = 0;
      if (tid < LBL) {
        const float w = w_edge[v];
        const float* __restrict__ Ac = A + tid;
        bv = __fadd_rn(s_b[0], __fmul_rn(w, Ac[0]));
        int lc = 1;
        for (; lc < 7; ++lc) {
          const float s = __fadd_rn(s_b[lc], __fmul_rn(w, Ac[(size_t)lc * LBL]));
          if (s > bv) { bv = s; bi = lc; }
        }
        for (; lc + 8 <= LBL; lc += 8) {
          const float a0 = Ac[(size_t)(lc + 0) * LBL];
          const float a1 = Ac[(size_t)(lc + 1) * LBL];
          const float a2 = Ac[(size_t)(lc + 2) * LBL];
          const float a3 = Ac[(size_t)(lc + 3) * LBL];
          const float a4 = Ac[(size_t)(lc + 4) * LBL];
          const float a5 = Ac[(size_t)(lc + 5) * LBL];
          const float a6 = Ac[(size_t)(lc + 6) * LBL];
          const float a7 = Ac[(size_t)(lc + 7) * LBL];
          const float s0 = __fadd_rn(s_b[lc + 0], __fmul_rn(w, a0));
          const float s1 = __fadd_rn(s_b[lc + 1], __fmul_rn(w, a1));
          const float s2 = __fadd_rn(s_b[lc + 2], __fmul_rn(w, a2));
          const float s3 = __fadd_rn(s_b[lc + 3], __fmul_rn(w, a3));
          const float s4 = __fadd_rn(s_b[lc + 4], __fmul_rn(w, a4));
          const float s5 = __fadd_rn(s_b[lc + 5], __fmul_rn(w, a5));
          const float s6 = __fadd_rn(s_b[lc + 6], __fmul_rn(w, a6));
          const float s7 = __fadd_rn(s_b[lc + 7], __fmul_rn(w, a7));
          if (s0 > bv) { bv = s0; bi = lc + 0; }
          if (s1 > bv) { bv = s1; bi = lc + 1; }
          if (s2 > bv) { bv = s2; bi = lc + 2; }
          if (s3 > bv) { bv = s3; bi = lc + 3; }
          if (s4 > bv) { bv = s4; bi = lc + 4; }
          if (s5 > bv) { bv = s5; bi = lc + 5; }
          if (s6 > bv) { bv = s6; bi = lc + 6; }
          if (s7 > bv) { bv = s7; bi = lc + 7; }
        }
      }
      // ptr store as aligned u32 pairs (backtrack data; no drain needed here)
      const int nbi = __shfl_down(bi, 1);   // uniform across all 384 threads
      if (tid < LBL && (tid & 1) == 0) {
        const unsigned pk = ((unsigned)bi & 0xFFFFu) | (((unsigned)nbi & 0xFFFFu) << 16);
        __hip_atomic_store((unsigned*)(ptrbuf + (size_t)v * PSTRIDE + tid), pk,
                           __ATOMIC_RELAXED, __HIP_MEMORY_SCOPE_AGENT);
      }

      const int p = parent[v] & (NN - 1);
      const int csp = childStart[p];
      int degp = childStart[p + 1] - csp;
      if (degp < 1) degp = 1;
      if (degp > 64) degp = 64;
      const bool isCarrier = ((childList[csp] & (NN - 1)) == v);

      if (!isCarrier) {
        // segment ends: publish msg via write-through, then release count
        if (tid < LBL)
          __hip_atomic_store((unsigned*)&msgbuf[(size_t)v * LBL + tid],
                             __float_as_uint(bv),
                             __ATOMIC_RELAXED, __HIP_MEMORY_SCOPE_AGENT);
        __syncthreads();
        if (tid == 0)
          __hip_atomic_fetch_add(&ready[p], 1,
                                 __ATOMIC_RELEASE, __HIP_MEMORY_SCOPE_AGENT);
        break;
      }

      // carrier: wait only for the OTHER children (if any), then fuse locally
      if (degp > 1 && tid == 0) {
        long long guard = 0;
        while (__hip_atomic_load(&ready[p], __ATOMIC_RELAXED,
                                 __HIP_MEMORY_SCOPE_AGENT) < degp - 1) {
          __builtin_amdgcn_s_sleep(4);
          if (++guard > 8000000LL) break;   // anti-hang escape (never expected)
        }
      }
      __syncthreads();   // also separates s_b reads (above) from next write

      if (tid < LBL) {
        float nb = __fadd_rn(unary[(size_t)p * LBL + tid], bv);  // carrier first
        for (int k = 1; k < degp; ++k) {
          const int ch = childList[csp + k] & (NN - 1);
          const unsigned um = __hip_atomic_load(
              (const unsigned*)&msgbuf[(size_t)ch * LBL + tid],
              __ATOMIC_RELAXED, __HIP_MEMORY_SCOPE_AGENT);
          nb = __fadd_rn(nb, __uint_as_float(um));
        }
        b = nb;
      }
      v = p;
    }
  }

  // -------- downward backtracking (the block that finished the root) --------
  if (!didRoot) return;
  __syncthreads();
  for (int lev = 1; lev < numLev; ++lev) {
    int ls = levStart[lev], le = levStart[lev + 1];
    if (ls < 0) ls = 0;
    if (le > NN) le = NN;
    for (int idx = ls + tid; idx < le; idx += 384) {
      const int c = levNodes[idx] & (NN - 1);
      int pl = s_lab[parent[c] & (NN - 1)];
      if (pl < 0) pl = 0;
      if (pl >= LBL) pl = LBL - 1;
      const unsigned pk = __hip_atomic_load(
          (const unsigned*)(ptrbuf + (size_t)c * PSTRIDE + (pl & ~1)),
          __ATOMIC_RELAXED, __HIP_MEMORY_SCOPE_AGENT);
      const int lab = (pl & 1) ? (int)(pk >> 16) : (int)(pk & 0xFFFFu);
      s_lab[c] = lab;
      labels[c] = lab;
    }
    __syncthreads();
  }
}

// ---------------------------------------------------------------------------
// Kernel 4: output fill (2*onehot - 1) * 1e5 (overwrites all of d_out)
// ---------------------------------------------------------------------------
__global__ void mrf_out_kernel(const int* __restrict__ labels, float* __restrict__ out)
{
  const int id = blockIdx.x * blockDim.x + threadIdx.x;
  if (id >= NN * LBL) return;
  const int c = id / LBL;
  const int l = id - c * LBL;
  out[id] = (l == labels[c]) ? 100000.0f : -100000.0f;
}

extern "C" void kernel_launch(void* const* d_in, const int* in_sizes, int n_in,
                              void* d_out, int out_size, void* d_ws, size_t ws_size,
                              hipStream_t stream)
{
  (void)in_sizes; (void)n_in; (void)out_size; (void)ws_size;
  const float* unary = (const float*)d_in[0];
  const float* dist  = (const float*)d_in[1];
  const float* A     = (const float*)d_in[2];
  float* out = (float*)d_out;

  char* ws = (char*)d_ws;
  size_t off = 0;
  auto take = [&](size_t bytes) -> void* {
    void* p = (void*)(ws + off);
    off += (bytes + 255) & ~(size_t)255;
    return p;
  };
  float* msgbuf = out;   // aliases d_out; fully overwritten by mrf_out_kernel
  unsigned short* ptrbuf = (unsigned short*)take((size_t)NN * PSTRIDE * sizeof(unsigned short));
  int*      compA      = (int*)     take(NN * sizeof(int));
  int*      compB      = (int*)     take(NN * sizeof(int));
  u64*      minEa      = (u64*)     take(NN * sizeof(u64));
  u64*      minEb      = (u64*)     take(NN * sizeof(u64));
  int*      eu         = (int*)     take(NN * sizeof(int));
  int*      ev         = (int*)     take(NN * sizeof(int));
  unsigned* ew         = (unsigned*)take(NN * sizeof(unsigned));
  int*      counters   = (int*)     take(256);
  int*      parent     = (int*)     take(NN * sizeof(int));
  int*      childStart = (int*)     take((NN + 1) * sizeof(int));
  int*      childList  = (int*)     take(NN * sizeof(int));
  int*      levStart   = (int*)     take((NN + 1) * sizeof(int));
  int*      levNodes   = (int*)     take(NN * sizeof(int));
  int*      segList    = (int*)     take(NN * sizeof(int));
  int*      labels     = (int*)     take(NN * sizeof(int));
  int*      meta       = (int*)     take(256);
  float*    w_edge     = (float*)   take(NN * sizeof(float));
  int*      ready      = (int*)     take(NN * sizeof(int));
  u64*      adjList    = (u64*)     take((size_t)2 * NN * sizeof(u64));

  hipLaunchKernelGGL(mrf_mst_init_kernel, dim3(4), dim3(1024), 0, stream,
                     compA, minEa, minEb, counters);

  for (int r = 0; r < MST_ROUNDS; ++r) {
    const int* compR = (r & 1) ? compB : compA;
    int*       compW = (r & 1) ? compA : compB;
    u64*       mcur  = (r & 1) ? minEb : minEa;
    u64*       mnext = (r & 1) ? minEa : minEb;
    hipLaunchKernelGGL(mrf_scan_kernel, dim3(128), dim3(1024), 0, stream,
                       dist, compR, mcur, counters, r);
    hipLaunchKernelGGL(mrf_hook_kernel, dim3(4), dim3(1024), 0, stream,
                       compR, compW, mcur, mnext, eu, ev, ew, counters, r);
  }

  hipLaunchKernelGGL(mrf_root_kernel, dim3(1), dim3(1024), 0, stream,
                     dist, eu, ev, ew, parent, childStart, childList,
                     levStart, levNodes, segList, meta, w_edge, adjList, ready);

  {
    void* args[] = {
      (void*)&unary, (void*)&A, (void*)&msgbuf, (void*)&ptrbuf,
      (void*)&parent, (void*)&childStart, (void*)&childList,
      (void*)&levStart, (void*)&levNodes, (void*)&segList, (void*)&w_edge,
      (void*)&labels, (void*)&meta, (void*)&ready
    };
    hipLaunchCooperativeKernel((void*)mrf_solve_kernel, dim3(256), dim3(384),
                               args, 0, stream);
  }

  const int total = NN * LBL;
  hipLaunchKernelGGL(mrf_out_kernel, dim3((total + 255) / 256), dim3(256), 0, stream,
                     labels, out);
}

// Round 8
// 980.923 us; speedup vs baseline: 6.5121x; 1.4326x over previous
//
#include <hip/hip_runtime.h>
#include <hip/hip_cooperative_groups.h>
#include <math.h>

namespace cg = cooperative_groups;
typedef unsigned long long u64;

#define NN 4096
#define LBL 343
#define PSTRIDE 344   // ptrbuf row stride (u16), even => aligned u32 pair stores
#define U64MAX 0xFFFFFFFFFFFFFFFFull
#define MST_ROUNDS 12 // components at least halve per round: 2^12 = 4096

// ---------------------------------------------------------------------------
// MST init: identity components, both minE parity buffers = MAX, counters.
// counters[0],[1] = root-count parity slots; counters[2] = edge cursor.
// ---------------------------------------------------------------------------
__global__ void mrf_mst_init_kernel(int* __restrict__ compA,
                                    u64* __restrict__ minEa, u64* __restrict__ minEb,
                                    int* __restrict__ counters)
{
  const int i = blockIdx.x * blockDim.x + threadIdx.x;
  if (i < NN) { compA[i] = i; minEa[i] = U64MAX; minEb[i] = U64MAX; }
  if (i == 0) { counters[0] = NN; counters[1] = NN; counters[2] = 0; }
}

// ---------------------------------------------------------------------------
// Boruvka phase 1 (per round): per-row min outgoing edge, one wave per row
// (256 blocks x 16 waves = 4096 waves), per-block LDS dedupe, atomicMin.
// ---------------------------------------------------------------------------
__global__ __launch_bounds__(1024) void mrf_scan_kernel(
    const float* __restrict__ dist, const int* __restrict__ compR,
    u64* __restrict__ minE, int* __restrict__ counters, int round)
{
  __shared__ int s_cc[16];
  __shared__ u64 s_cv[16];

  if (blockIdx.x == 0 && threadIdx.x == 0) counters[round & 1] = 0;
  if (round > 0 && counters[(round - 1) & 1] <= 1) return;

  const int i    = (blockIdx.x * 1024 + threadIdx.x) >> 6;  // row 0..4095
  const int lane = threadIdx.x & 63;
  const int wib  = threadIdx.x >> 6;

  const int ci = compR[i];
  const float4* rowp = (const float4*)(dist + (size_t)i * NN);
  const int4* cp = (const int4*)compR;
  u64 best = U64MAX;
  #pragma unroll 4
  for (int k = 0; k < 16; ++k) {
    const int q = k * 64 + lane;
    const float4 dv = rowp[q];
    const int4 cv = cp[q];
    const int j0 = q * 4;
    if (cv.x != ci) { const u64 p = ((u64)__float_as_uint(dv.x) << 24) | ((u64)i << 12) | (u64)(j0    ); best = best < p ? best : p; }
    if (cv.y != ci) { const u64 p = ((u64)__float_as_uint(dv.y) << 24) | ((u64)i << 12) | (u64)(j0 + 1); best = best < p ? best : p; }
    if (cv.z != ci) { const u64 p = ((u64)__float_as_uint(dv.z) << 24) | ((u64)i << 12) | (u64)(j0 + 2); best = best < p ? best : p; }
    if (cv.w != ci) { const u64 p = ((u64)__float_as_uint(dv.w) << 24) | ((u64)i << 12) | (u64)(j0 + 3); best = best < p ? best : p; }
  }
  #pragma unroll
  for (int sh = 32; sh >= 1; sh >>= 1) {
    const u64 o = __shfl_down(best, sh);
    best = best < o ? best : o;
  }
  if (lane == 0) {
    s_cc[wib] = (best == U64MAX) ? -1 : ci;
    s_cv[wib] = best;
  }
  __syncthreads();
  if (threadIdx.x == 0) {
    for (int a = 0; a < 16; ++a) {
      const int c = s_cc[a];
      if (c < 0) continue;
      bool dup = false;
      for (int b2 = 0; b2 < a; ++b2) if (s_cc[b2] == c) { dup = true; break; }
      if (dup) continue;
      u64 b = s_cv[a];
      for (int b2 = a + 1; b2 < 16; ++b2)
        if (s_cc[b2] == c && s_cv[b2] < b) b = s_cv[b2];
      atomicMin(&minE[c & (NN - 1)], b);
    }
  }
}

// ---------------------------------------------------------------------------
// Boruvka phases 2+3 fused (unchanged, passing).
// ---------------------------------------------------------------------------
__global__ __launch_bounds__(1024) void mrf_hook_kernel(
    const int* __restrict__ compR, int* __restrict__ compW,
    const u64* __restrict__ minE, u64* __restrict__ minEnext,
    int* __restrict__ eu, int* __restrict__ ev, unsigned* __restrict__ ew,
    int* __restrict__ counters, int round)
{
  if (round > 0 && counters[(round - 1) & 1] <= 1) return;
  const int i = blockIdx.x * 1024 + threadIdx.x;
  if (i >= NN) return;
  minEnext[i] = U64MAX;

  const int r0 = compR[i];
  int cur = r0;
  for (int guard = 0; guard < NN + 2; ++guard) {
    const u64 e = minE[cur];
    if (e == U64MAX) break;
    const int v = (int)(e & 0xFFF);
    const int t = compR[v];
    if (t == cur) break;
    const u64 te = minE[t];
    if (te != U64MAX) {
      const int tv = (int)(te & 0xFFF);
      if (compR[tv] == cur && cur < t) break;    // mutual pair: cur wins
    }
    cur = t;
  }
  compW[i] = cur;
  if (cur == i) atomicAdd(&counters[round & 1], 1);

  if (r0 == i) {
    const u64 e = minE[i];
    if (e != U64MAX) {
      const int v = (int)(e & 0xFFF);
      const int u = (int)((e >> 12) & 0xFFF);
      const unsigned wb = (unsigned)(e >> 24);
      const int t = compR[v];
      bool mutual = false;
      const u64 te = minE[t];
      if (te != U64MAX) {
        const int tv = (int)(te & 0xFFF);
        mutual = (compR[tv] == i);
      }
      if (!(mutual && i < t)) {
        const int slot = atomicAdd(&counters[2], 1);
        if (slot < NN) { eu[slot] = u; ev[slot] = v; ew[slot] = wb; }
      }
    }
  }
}

// ---------------------------------------------------------------------------
// block-wide exclusive scan over 4096 LDS ints (1024 threads, 4/thread)
// ---------------------------------------------------------------------------
__device__ __forceinline__ void scan4096(int* arr, int* tmp16, int tid)
{
  __syncthreads();
  const int base = tid * 4;
  const int c0 = arr[base], c1 = arr[base + 1], c2 = arr[base + 2], c3 = arr[base + 3];
  const int lsum = c0 + c1 + c2 + c3;
  const int lane = tid & 63, wid = tid >> 6;
  int incl = lsum;
  #pragma unroll
  for (int o = 1; o < 64; o <<= 1) {
    const int t = __shfl_up(incl, o);
    if (lane >= o) incl += t;
  }
  if (lane == 63) tmp16[wid] = incl;
  __syncthreads();
  if (tid == 0) {
    int run = 0;
    for (int w = 0; w < 16; ++w) { const int t = tmp16[w]; tmp16[w] = run; run += t; }
  }
  __syncthreads();
  const int excl = tmp16[wid] + incl - lsum;
  arr[base]     = excl;
  arr[base + 1] = excl + c0;
  arr[base + 2] = excl + c0 + c1;
  arr[base + 3] = excl + c0 + c1 + c2;
  __syncthreads();
}

// ---------------------------------------------------------------------------
// Kernel 2 (single block): root MST at 0, child lists desc-(wbits,idx)
// (== reversed Prim order), level buckets, carrier-segment list sorted by
// depth-of-last-node DESC (topological order of segments), w_edge, ready=0.
// ---------------------------------------------------------------------------
__global__ __launch_bounds__(1024) void mrf_root_kernel(
    const float* __restrict__ dist,
    const int* __restrict__ eu, const int* __restrict__ ev, const unsigned* __restrict__ ew,
    int* __restrict__ parent_g, int* __restrict__ childStart, int* __restrict__ childList,
    int* __restrict__ levStart, int* __restrict__ levNodes, int* __restrict__ segList,
    int* __restrict__ meta, float* __restrict__ w_edge,
    u64* __restrict__ adjList, int* __restrict__ ready)
{
  __shared__ int s_deg[NN];
  __shared__ int s_start[NN];
  __shared__ int s_cur[NN];
  __shared__ int s_parent[NN];
  __shared__ unsigned short s_dep[NN];
  __shared__ unsigned short s_fr[2][NN];
  __shared__ int s_tmp16[16];
  __shared__ int s_fcnt, s_nf;

  const int tid = threadIdx.x;

  for (int j = tid; j < NN; j += 1024) ready[j] = 0;   // fresh every call

  // ---- adjacency ----
  for (int j = tid; j < NN; j += 1024) s_deg[j] = 0;
  __syncthreads();
  for (int e = tid; e < NN - 1; e += 1024) {
    atomicAdd(&s_deg[eu[e] & (NN - 1)], 1);
    atomicAdd(&s_deg[ev[e] & (NN - 1)], 1);
  }
  __syncthreads();
  for (int j = tid; j < NN; j += 1024) s_start[j] = s_deg[j];
  scan4096(s_start, s_tmp16, tid);
  for (int j = tid; j < NN; j += 1024) s_cur[j] = s_start[j];
  __syncthreads();
  for (int e = tid; e < NN - 1; e += 1024) {
    const int u = eu[e] & (NN - 1), v = ev[e] & (NN - 1);
    const u64 wb = (u64)ew[e];
    const int p1 = atomicAdd(&s_cur[u], 1);
    adjList[p1] = (wb << 12) | (u64)v;
    const int p2 = atomicAdd(&s_cur[v], 1);
    adjList[p2] = (wb << 12) | (u64)u;
  }
  __syncthreads();

  // ---- BFS from node 0 ----
  for (int j = tid; j < NN; j += 1024) { s_parent[j] = 0; s_dep[j] = 0; }
  if (tid == 0) { s_fcnt = 1; s_nf = 0; s_fr[0][0] = 0; }
  __syncthreads();
  int cur = 0, lev = 0;
  while (true) {
    const int fcnt = s_fcnt;
    if (fcnt == 0) break;
    for (int idx = tid; idx < fcnt; idx += 1024) {
      const int x = s_fr[cur][idx];
      const int st = s_start[x], dg = s_deg[x];
      for (int a = 0; a < dg; ++a) {
        const u64 ent = adjList[st + a];
        const int nb = (int)(ent & 0xFFF);
        if (nb != s_parent[x] || x == 0) {
          s_parent[nb] = x;
          s_dep[nb] = (unsigned short)(lev + 1);
          const int slot = atomicAdd(&s_nf, 1);
          s_fr[1 - cur][slot] = (unsigned short)nb;
        }
      }
    }
    __syncthreads();
    if (tid == 0) { s_fcnt = s_nf; s_nf = 0; }
    ++lev;
    cur ^= 1;
    __syncthreads();
  }
  const int numLev = lev;
  if (tid == 0) { s_parent[0] = 0; meta[0] = numLev; }
  __syncthreads();

  // ---- childStart ----
  int* s_cs2 = (int*)s_fr;     // 4096 ints, overlays frontier memory
  for (int j = tid; j < NN; j += 1024) s_cs2[j] = s_deg[j] - (j != 0 ? 1 : 0);
  scan4096(s_cs2, s_tmp16, tid);
  for (int j = tid; j < NN; j += 1024) childStart[j] = s_cs2[j];
  if (tid == 0) childStart[NN] = NN - 1;
  __syncthreads();

  // ---- children sorted descending by (wbits, idx) ----
  for (int p = tid; p < NN; p += 1024) {
    const int st = s_start[p], dg = s_deg[p], cs = s_cs2[p];
    const int par = s_parent[p];
    u64 buf[16];
    int m = 0;
    for (int a = 0; a < dg; ++a) {
      const u64 ent = adjList[st + a];
      const int nb = (int)(ent & 0xFFF);
      if (p != 0 && nb == par) continue;
      if (m < 16) {
        int q = m;
        while (q > 0 && buf[q - 1] < ent) { buf[q] = buf[q - 1]; --q; }
        buf[q] = ent;
        ++m;
      } else {
        childList[cs + m] = nb;
        ++m;
      }
    }
    const int lim = m < 16 ? m : 16;
    for (int k = 0; k < lim; ++k) childList[cs + k] = (int)(buf[k] & 0xFFF);
  }

  // ---- level buckets ----
  for (int j = tid; j < NN; j += 1024) s_cur[j] = 0;
  __syncthreads();
  for (int j = tid; j < NN; j += 1024) atomicAdd(&s_cur[s_dep[j]], 1);
  scan4096(s_cur, s_tmp16, tid);
  for (int j = tid; j < NN; j += 1024) { levStart[j] = s_cur[j]; s_start[j] = s_cur[j]; }
  if (tid == 0) levStart[NN] = NN;
  __syncthreads();
  for (int j = tid; j < NN; j += 1024) {
    const int pos = atomicAdd(&s_start[s_dep[j]], 1);
    levNodes[pos] = j;
  }
  __syncthreads();

  // ---- carrier segments: one per leaf; key = depth of segment's LAST node.
  if (tid == 0) s_nf = 0;
  for (int j = tid; j < NN; j += 1024) s_cur[j] = 0;   // bucket counts
  __syncthreads();
  for (int j = tid; j < NN; j += 1024) {
    const int ce = (j == NN - 1) ? (NN - 1) : s_cs2[j + 1];
    int key = -1;
    if (ce - s_cs2[j] == 0) {          // leaf
      int c = j;
      while (c != 0) {
        const int par = s_parent[c];
        if (childList[s_cs2[par]] != c) break;   // c is not the carrier
        c = par;
      }
      key = s_dep[c];
      atomicAdd(&s_cur[numLev - 1 - key], 1);
      atomicAdd(&s_nf, 1);
    }
    s_deg[j] = key;                    // s_deg reused as per-leaf key store
  }
  scan4096(s_cur, s_tmp16, tid);
  for (int j = tid; j < NN; j += 1024) s_start[j] = s_cur[j];
  __syncthreads();
  for (int j = tid; j < NN; j += 1024) {
    const int key = s_deg[j];
    if (key >= 0) {
      const int pos = atomicAdd(&s_start[numLev - 1 - key], 1);
      segList[pos] = j;
    }
  }
  if (tid == 0) meta[1] = s_nf;

  // ---- outputs ----
  for (int j = tid; j < NN; j += 1024) {
    parent_g[j] = s_parent[j];
    w_edge[j] = (j == 0) ? 0.0f
                         : expf(-dist[(size_t)j * NN + s_parent[j]] / 0.18f);
  }
}

// ---------------------------------------------------------------------------
// Kernel 3 (cooperative, carrier-chain dataflow, 768 threads = 12 waves):
// per-node argmax split into two lc-halves across the wave set (balanced
// 3 waves/SIMD) with exact first-max LDS combine (h=0 = lower lc wins ties).
// Chains keep the message in registers; branch nodes poll; non-carrier ends
// publish via write-through L3 atomics. msgbuf aliases d_out.
// ---------------------------------------------------------------------------
__global__ __launch_bounds__(768) void mrf_solve_kernel(
    const float* __restrict__ unary, const float* __restrict__ A,
    float* __restrict__ msgbuf, unsigned short* __restrict__ ptrbuf,
    const int* __restrict__ parent, const int* __restrict__ childStart,
    const int* __restrict__ childList, const int* __restrict__ levStart,
    const int* __restrict__ levNodes, const int* __restrict__ segList,
    const float* __restrict__ w_edge,
    int* __restrict__ labels, const int* __restrict__ meta,
    int* __restrict__ ready)
{
  __shared__ float s_b[LBL];
  __shared__ int s_lab[NN];
  __shared__ float s_pv[2][384];
  __shared__ int   s_pi[2][384];
  const int tid = threadIdx.x;
  const int h   = (tid >= 384) ? 1 : 0;     // lc-half
  const int lp  = tid - h * 384;            // label-parent slot [0,384)
  const int lc0 = h ? 172 : 0;
  const int lc1 = h ? LBL : 172;

  int numLev = meta[0];
  if (numLev < 1) numLev = 1;
  if (numLev > NN) numLev = NN;
  int numSegs = meta[1];
  if (numSegs < 1) numSegs = 1;
  if (numSegs > NN) numSegs = NN;

  bool didRoot = false;

  for (int sidx = blockIdx.x; sidx < numSegs && !didRoot; sidx += gridDim.x) {
    int v = segList[sidx] & (NN - 1);
    float b = (tid < LBL) ? unary[(size_t)v * LBL + tid] : 0.0f;  // leaf belief

    while (true) {
      if (tid < LBL) s_b[tid] = b;
      __syncthreads();

      if (v == 0) {
        if (tid == 0) {
          float bv = s_b[0]; int bi = 0;
          for (int l = 1; l < LBL; ++l)
            if (s_b[l] > bv) { bv = s_b[l]; bi = l; }
          labels[0] = bi;
          s_lab[0] = bi;
        }
        __syncthreads();
        didRoot = true;
        break;
      }

      // ---- partial argmax over this thread's lc-half (exact serial order) ----
      {
        float bv = 0.0f; int bi = lc0;
        if (lp < LBL) {
          const float w = w_edge[v];
          const float* __restrict__ Ac = A + lp;
          bv = __fadd_rn(s_b[lc0], __fmul_rn(w, Ac[(size_t)lc0 * LBL]));
          int lc = lc0 + 1;
          for (; ((lc1 - lc) & 7) != 0; ++lc) {       // peel to multiple of 8
            const float s = __fadd_rn(s_b[lc], __fmul_rn(w, Ac[(size_t)lc * LBL]));
            if (s > bv) { bv = s; bi = lc; }
          }
          for (; lc < lc1; lc += 8) {                 // 8 independent loads
            const float a0 = Ac[(size_t)(lc + 0) * LBL];
            const float a1 = Ac[(size_t)(lc + 1) * LBL];
            const float a2 = Ac[(size_t)(lc + 2) * LBL];
            const float a3 = Ac[(size_t)(lc + 3) * LBL];
            const float a4 = Ac[(size_t)(lc + 4) * LBL];
            const float a5 = Ac[(size_t)(lc + 5) * LBL];
            const float a6 = Ac[(size_t)(lc + 6) * LBL];
            const float a7 = Ac[(size_t)(lc + 7) * LBL];
            const float s0 = __fadd_rn(s_b[lc + 0], __fmul_rn(w, a0));
            const float s1 = __fadd_rn(s_b[lc + 1], __fmul_rn(w, a1));
            const float s2 = __fadd_rn(s_b[lc + 2], __fmul_rn(w, a2));
            const float s3 = __fadd_rn(s_b[lc + 3], __fmul_rn(w, a3));
            const float s4 = __fadd_rn(s_b[lc + 4], __fmul_rn(w, a4));
            const float s5 = __fadd_rn(s_b[lc + 5], __fmul_rn(w, a5));
            const float s6 = __fadd_rn(s_b[lc + 6], __fmul_rn(w, a6));
            const float s7 = __fadd_rn(s_b[lc + 7], __fmul_rn(w, a7));
            if (s0 > bv) { bv = s0; bi = lc + 0; }
            if (s1 > bv) { bv = s1; bi = lc + 1; }
            if (s2 > bv) { bv = s2; bi = lc + 2; }
            if (s3 > bv) { bv = s3; bi = lc + 3; }
            if (s4 > bv) { bv = s4; bi = lc + 4; }
            if (s5 > bv) { bv = s5; bi = lc + 5; }
            if (s6 > bv) { bv = s6; bi = lc + 6; }
            if (s7 > bv) { bv = s7; bi = lc + 7; }
          }
        }
        s_pv[h][lp] = bv;
        s_pi[h][lp] = bi;
      }
      __syncthreads();

      // ---- combine halves: strict >, h=0 (lower lc) wins ties == serial ----
      float fbv = 0.0f; int fbi = 0;
      if (tid < LBL) {
        fbv = s_pv[0][tid]; fbi = s_pi[0][tid];
        const float v1 = s_pv[1][tid];
        if (v1 > fbv) { fbv = v1; fbi = s_pi[1][tid]; }
      }
      // ptr store as aligned u32 pairs (even tid pairs with tid+1, same wave)
      const int nbi = __shfl_down(fbi, 1);
      if (tid < LBL && (tid & 1) == 0) {
        const unsigned pk = ((unsigned)fbi & 0xFFFFu) | (((unsigned)nbi & 0xFFFFu) << 16);
        __hip_atomic_store((unsigned*)(ptrbuf + (size_t)v * PSTRIDE + tid), pk,
                           __ATOMIC_RELAXED, __HIP_MEMORY_SCOPE_AGENT);
      }

      const int p = parent[v] & (NN - 1);
      const int csp = childStart[p];
      int degp = childStart[p + 1] - csp;
      if (degp < 1) degp = 1;
      if (degp > 64) degp = 64;
      const bool isCarrier = ((childList[csp] & (NN - 1)) == v);

      if (!isCarrier) {
        // segment ends: publish msg via write-through, then release count
        if (tid < LBL)
          __hip_atomic_store((unsigned*)&msgbuf[(size_t)v * LBL + tid],
                             __float_as_uint(fbv),
                             __ATOMIC_RELAXED, __HIP_MEMORY_SCOPE_AGENT);
        __syncthreads();
        if (tid == 0)
          __hip_atomic_fetch_add(&ready[p], 1,
                                 __ATOMIC_RELEASE, __HIP_MEMORY_SCOPE_AGENT);
        break;
      }

      // carrier: wait only for the OTHER children (if any), then fuse locally
      if (degp > 1 && tid == 0) {
        long long guard = 0;
        while (__hip_atomic_load(&ready[p], __ATOMIC_RELAXED,
                                 __HIP_MEMORY_SCOPE_AGENT) < degp - 1) {
          __builtin_amdgcn_s_sleep(1);
          if (++guard > 30000000LL) break;   // anti-hang escape (never expected)
        }
      }
      __syncthreads();   // also separates s_b/s_pv reads from next write

      if (tid < LBL) {
        float nb = __fadd_rn(unary[(size_t)p * LBL + tid], fbv);  // carrier first
        for (int k = 1; k < degp; ++k) {
          const int ch = childList[csp + k] & (NN - 1);
          const unsigned um = __hip_atomic_load(
              (const unsigned*)&msgbuf[(size_t)ch * LBL + tid],
              __ATOMIC_RELAXED, __HIP_MEMORY_SCOPE_AGENT);
          nb = __fadd_rn(nb, __uint_as_float(um));
        }
        b = nb;
      }
      v = p;
    }
  }

  // -------- downward backtracking (the block that finished the root) --------
  if (!didRoot) return;
  __syncthreads();
  for (int lev = 1; lev < numLev; ++lev) {
    int ls = levStart[lev], le = levStart[lev + 1];
    if (ls < 0) ls = 0;
    if (le > NN) le = NN;
    for (int idx = ls + tid; idx < le; idx += 768) {
      const int c = levNodes[idx] & (NN - 1);
      int pl = s_lab[parent[c] & (NN - 1)];
      if (pl < 0) pl = 0;
      if (pl >= LBL) pl = LBL - 1;
      const unsigned pk = __hip_atomic_load(
          (const unsigned*)(ptrbuf + (size_t)c * PSTRIDE + (pl & ~1)),
          __ATOMIC_RELAXED, __HIP_MEMORY_SCOPE_AGENT);
      const int lab = (pl & 1) ? (int)(pk >> 16) : (int)(pk & 0xFFFFu);
      s_lab[c] = lab;
      labels[c] = lab;
    }
    __syncthreads();
  }
}

// ---------------------------------------------------------------------------
// Kernel 4: output fill (2*onehot - 1) * 1e5 (overwrites all of d_out)
// ---------------------------------------------------------------------------
__global__ void mrf_out_kernel(const int* __restrict__ labels, float* __restrict__ out)
{
  const int id = blockIdx.x * blockDim.x + threadIdx.x;
  if (id >= NN * LBL) return;
  const int c = id / LBL;
  const int l = id - c * LBL;
  out[id] = (l == labels[c]) ? 100000.0f : -100000.0f;
}

extern "C" void kernel_launch(void* const* d_in, const int* in_sizes, int n_in,
                              void* d_out, int out_size, void* d_ws, size_t ws_size,
                              hipStream_t stream)
{
  (void)in_sizes; (void)n_in; (void)out_size; (void)ws_size;
  const float* unary = (const float*)d_in[0];
  const float* dist  = (const float*)d_in[1];
  const float* A     = (const float*)d_in[2];
  float* out = (float*)d_out;

  char* ws = (char*)d_ws;
  size_t off = 0;
  auto take = [&](size_t bytes) -> void* {
    void* p = (void*)(ws + off);
    off += (bytes + 255) & ~(size_t)255;
    return p;
  };
  float* msgbuf = out;   // aliases d_out; fully overwritten by mrf_out_kernel
  unsigned short* ptrbuf = (unsigned short*)take((size_t)NN * PSTRIDE * sizeof(unsigned short));
  int*      compA      = (int*)     take(NN * sizeof(int));
  int*      compB      = (int*)     take(NN * sizeof(int));
  u64*      minEa      = (u64*)     take(NN * sizeof(u64));
  u64*      minEb      = (u64*)     take(NN * sizeof(u64));
  int*      eu         = (int*)     take(NN * sizeof(int));
  int*      ev         = (int*)     take(NN * sizeof(int));
  unsigned* ew         = (unsigned*)take(NN * sizeof(unsigned));
  int*      counters   = (int*)     take(256);
  int*      parent     = (int*)     take(NN * sizeof(int));
  int*      childStart = (int*)     take((NN + 1) * sizeof(int));
  int*      childList  = (int*)     take(NN * sizeof(int));
  int*      levStart   = (int*)     take((NN + 1) * sizeof(int));
  int*      levNodes   = (int*)     take(NN * sizeof(int));
  int*      segList    = (int*)     take(NN * sizeof(int));
  int*      labels     = (int*)     take(NN * sizeof(int));
  int*      meta       = (int*)     take(256);
  float*    w_edge     = (float*)   take(NN * sizeof(float));
  int*      ready      = (int*)     take(NN * sizeof(int));
  u64*      adjList    = (u64*)     take((size_t)2 * NN * sizeof(u64));

  hipLaunchKernelGGL(mrf_mst_init_kernel, dim3(4), dim3(1024), 0, stream,
                     compA, minEa, minEb, counters);

  for (int r = 0; r < MST_ROUNDS; ++r) {
    const int* compR = (r & 1) ? compB : compA;
    int*       compW = (r & 1) ? compA : compB;
    u64*       mcur  = (r & 1) ? minEb : minEa;
    u64*       mnext = (r & 1) ? minEa : minEb;
    hipLaunchKernelGGL(mrf_scan_kernel, dim3(256), dim3(1024), 0, stream,
                       dist, compR, mcur, counters, r);
    hipLaunchKernelGGL(mrf_hook_kernel, dim3(4), dim3(1024), 0, stream,
                       compR, compW, mcur, mnext, eu, ev, ew, counters, r);
  }

  hipLaunchKernelGGL(mrf_root_kernel, dim3(1), dim3(1024), 0, stream,
                     dist, eu, ev, ew, parent, childStart, childList,
                     levStart, levNodes, segList, meta, w_edge, adjList, ready);

  {
    void* args[] = {
      (void*)&unary, (void*)&A, (void*)&msgbuf, (void*)&ptrbuf,
      (void*)&parent, (void*)&childStart, (void*)&childList,
      (void*)&levStart, (void*)&levNodes, (void*)&segList, (void*)&w_edge,
      (void*)&labels, (void*)&meta, (void*)&ready
    };
    hipLaunchCooperativeKernel((void*)mrf_solve_kernel, dim3(256), dim3(768),
                               args, 0, stream);
  }

  const int total = NN * LBL;
  hipLaunchKernelGGL(mrf_out_kernel, dim3((total + 255) / 256), dim3(256), 0, stream,
                     labels, out);
}